// Round 1
// baseline (101.581 us; speedup 1.0000x reference)
//
#include <hip/hip_runtime.h>
#include <hip/hip_bf16.h>

#define SDIM 2048
#define DDIM 64
#define HNUM 8
#define QBLK 64
#define KVBLK 64
#define NTHR 256
#define LDP 72
#define NEGV -1.0e9f

typedef __bf16 bf16x8 __attribute__((ext_vector_type(8)));
typedef float f32x4 __attribute__((ext_vector_type(4)));
typedef unsigned short u16;
typedef u16 u16x4 __attribute__((ext_vector_type(4)));
typedef u16 u16x8 __attribute__((ext_vector_type(8)));

__device__ __forceinline__ u16 f2bf(float f) {
    unsigned u = __float_as_uint(f);
    u += 0x7FFFu + ((u >> 16) & 1u);
    return (u16)(u >> 16);
}
__device__ __forceinline__ float bf2f(u16 h) {
    return __uint_as_float((unsigned)h << 16);
}

union U8 { u16 u[8]; u16x8 v; bf16x8 b; };
union U4 { u16 u[4]; u16x4 v; };

__global__ __launch_bounds__(NTHR, 2)
void attn64(const float* __restrict__ Q, const float* __restrict__ K,
            const float* __restrict__ V, const int* __restrict__ MK,
            float* __restrict__ O) {
    // K tile (hi/lo) natural [kv][d]; V tile transposed [d][kv] (hi/lo); P [q][kv]
    __shared__ __align__(16) u16 sK[2][KVBLK][LDP];
    __shared__ __align__(16) u16 sV[2][DDIM][LDP];
    __shared__ __align__(16) u16 sP[QBLK][LDP];
    __shared__ __align__(16) int sM[KVBLK];

    const int tid = threadIdx.x;
    const int wv  = tid >> 6;
    const int ln  = tid & 63;
    const int g   = ln >> 4;   // lane group 0..3
    const int mi  = ln & 15;   // lane-low 0..15

    const int bh = blockIdx.y;         // 0..15
    const int b  = bh >> 3;            // H = 8
    const int qbase = blockIdx.x * QBLK;
    const size_t base = (size_t)bh * SDIM * DDIM;
    const int qrow = qbase + 16 * wv + mi;   // this lane's q row (N-index)

    // ---- Q fragments in registers, hi/lo split, pre-scaled by 1/TEMPERATURE ----
    bf16x8 qhi[2], qlo[2];
    {
        const float* qp = Q + base + (size_t)qrow * DDIM;
        #pragma unroll
        for (int ks = 0; ks < 2; ++ks) {
            const float4 a = *(const float4*)(qp + 32 * ks + 8 * g);
            const float4 c = *(const float4*)(qp + 32 * ks + 8 * g + 4);
            float f[8] = {a.x, a.y, a.z, a.w, c.x, c.y, c.z, c.w};
            U8 h, l;
            #pragma unroll
            for (int e = 0; e < 8; ++e) {
                float fs = f[e] * 0.125f;
                u16 hh = f2bf(fs);
                h.u[e] = hh;
                l.u[e] = f2bf(fs - bf2f(hh));
            }
            qhi[ks] = h.b;
            qlo[ks] = l.b;
        }
    }

    f32x4 zero4 = {0.f, 0.f, 0.f, 0.f};
    f32x4 oacc[4];
    #pragma unroll
    for (int i = 0; i < 4; ++i) oacc[i] = zero4;
    float mrun = -INFINITY;
    float lrun = 0.f;

    for (int kt = 0; kt < SDIM / KVBLK; ++kt) {
        const int kv0 = kt * KVBLK;
        __syncthreads();   // previous tile's LDS reads complete

        // ---- stage K tile: [kv][d] hi/lo, coalesced ----
        {
            const int row = tid >> 2, c0 = (tid & 3) * 16;
            const float* kp = K + base + (size_t)(kv0 + row) * DDIM + c0;
            #pragma unroll
            for (int half = 0; half < 2; ++half) {
                const float4 a = *(const float4*)(kp + 8 * half);
                const float4 c = *(const float4*)(kp + 8 * half + 4);
                float f[8] = {a.x, a.y, a.z, a.w, c.x, c.y, c.z, c.w};
                U8 h, l;
                #pragma unroll
                for (int e = 0; e < 8; ++e) {
                    u16 hh = f2bf(f[e]);
                    h.u[e] = hh;
                    l.u[e] = f2bf(f[e] - bf2f(hh));
                }
                *(u16x8*)&sK[0][row][c0 + 8 * half] = h.v;
                *(u16x8*)&sK[1][row][c0 + 8 * half] = l.v;
            }
        }
        // ---- stage V tile transposed: Vt[d][kv] hi/lo ----
        {
            const int kvl = tid & 63, d0 = (tid >> 6) * 16;
            const float* vp = V + base + (size_t)(kv0 + kvl) * DDIM + d0;
            #pragma unroll
            for (int jj = 0; jj < 4; ++jj) {
                const float4 a = *(const float4*)(vp + 4 * jj);
                float f[4] = {a.x, a.y, a.z, a.w};
                #pragma unroll
                for (int e = 0; e < 4; ++e) {
                    u16 hh = f2bf(f[e]);
                    sV[0][d0 + 4 * jj + e][kvl] = hh;
                    sV[1][d0 + 4 * jj + e][kvl] = f2bf(f[e] - bf2f(hh));
                }
            }
        }
        if (tid < KVBLK) sM[tid] = MK[(size_t)b * SDIM + kv0 + tid];
        __syncthreads();

        // ---- S^T = K_tile · Q^T  (M=kv, N=q, K-dim=d) ----
        float s[4][4];
        #pragma unroll
        for (int mt = 0; mt < 4; ++mt) {
            f32x4 acc = zero4;
            #pragma unroll
            for (int ks = 0; ks < 2; ++ks) {
                const bf16x8 ahi = *(const bf16x8*)&sK[0][16 * mt + mi][32 * ks + 8 * g];
                const bf16x8 alo = *(const bf16x8*)&sK[1][16 * mt + mi][32 * ks + 8 * g];
                acc = __builtin_amdgcn_mfma_f32_16x16x32_bf16(ahi, qhi[ks], acc, 0, 0, 0);
                acc = __builtin_amdgcn_mfma_f32_16x16x32_bf16(alo, qhi[ks], acc, 0, 0, 0);
                acc = __builtin_amdgcn_mfma_f32_16x16x32_bf16(ahi, qlo[ks], acc, 0, 0, 0);
            }
            const int4 mk = *(const int4*)&sM[16 * mt + 4 * g];
            s[mt][0] = mk.x ? acc[0] : NEGV;
            s[mt][1] = mk.y ? acc[1] : NEGV;
            s[mt][2] = mk.z ? acc[2] : NEGV;
            s[mt][3] = mk.w ? acc[3] : NEGV;
        }

        // ---- online softmax (lane owns q=mi; kv spread over 4 lane-groups) ----
        float tm = s[0][0];
        #pragma unroll
        for (int mt = 0; mt < 4; ++mt)
            #pragma unroll
            for (int r = 0; r < 4; ++r) tm = fmaxf(tm, s[mt][r]);
        tm = fmaxf(tm, __shfl_xor(tm, 16));
        tm = fmaxf(tm, __shfl_xor(tm, 32));
        const float mnew = fmaxf(mrun, tm);
        const float corr = __expf(mrun - mnew);   // first tile: exp(-inf)=0
        mrun = mnew;
        lrun *= corr;
        #pragma unroll
        for (int mt = 0; mt < 4; ++mt) {
            oacc[mt][0] *= corr; oacc[mt][1] *= corr;
            oacc[mt][2] *= corr; oacc[mt][3] *= corr;
        }
        #pragma unroll
        for (int mt = 0; mt < 4; ++mt) {
            U4 pw;
            #pragma unroll
            for (int r = 0; r < 4; ++r) {
                float p = __expf(s[mt][r] - mnew);
                u16 pb = f2bf(p);
                pw.u[r] = pb;
                lrun += bf2f(pb);   // denominator matches the bf16 P fed to MFMA
            }
            *(u16x4*)&sP[16 * wv + mi][16 * mt + 4 * g] = pw.v;
        }
        __syncthreads();

        // ---- O^T += V^T · P^T  (M=d, N=q, K-dim=kv) ----
        const bf16x8 pf0 = *(const bf16x8*)&sP[16 * wv + mi][8 * g];
        const bf16x8 pf1 = *(const bf16x8*)&sP[16 * wv + mi][32 + 8 * g];
        #pragma unroll
        for (int mt = 0; mt < 4; ++mt) {
            const bf16x8 vh0 = *(const bf16x8*)&sV[0][16 * mt + mi][8 * g];
            const bf16x8 vl0 = *(const bf16x8*)&sV[1][16 * mt + mi][8 * g];
            const bf16x8 vh1 = *(const bf16x8*)&sV[0][16 * mt + mi][32 + 8 * g];
            const bf16x8 vl1 = *(const bf16x8*)&sV[1][16 * mt + mi][32 + 8 * g];
            oacc[mt] = __builtin_amdgcn_mfma_f32_16x16x32_bf16(vh0, pf0, oacc[mt], 0, 0, 0);
            oacc[mt] = __builtin_amdgcn_mfma_f32_16x16x32_bf16(vl0, pf0, oacc[mt], 0, 0, 0);
            oacc[mt] = __builtin_amdgcn_mfma_f32_16x16x32_bf16(vh1, pf1, oacc[mt], 0, 0, 0);
            oacc[mt] = __builtin_amdgcn_mfma_f32_16x16x32_bf16(vl1, pf1, oacc[mt], 0, 0, 0);
        }
    }

    // ---- finalize: reduce partial row-sums across lane-groups, normalize, store ----
    lrun += __shfl_xor(lrun, 16);
    lrun += __shfl_xor(lrun, 32);
    const float inv = 1.0f / lrun;
    float* op = O + base + (size_t)qrow * DDIM;
    #pragma unroll
    for (int mt = 0; mt < 4; ++mt) {
        float4 o;
        o.x = oacc[mt][0] * inv;
        o.y = oacc[mt][1] * inv;
        o.z = oacc[mt][2] * inv;
        o.w = oacc[mt][3] * inv;
        *(float4*)(op + 16 * mt + 4 * g) = o;   // d = 16*mt + 4*g + r, contiguous
    }
}

extern "C" void kernel_launch(void* const* d_in, const int* in_sizes, int n_in,
                              void* d_out, int out_size, void* d_ws, size_t ws_size,
                              hipStream_t stream) {
    const float* q  = (const float*)d_in[0];
    const float* k  = (const float*)d_in[1];
    const float* v  = (const float*)d_in[2];
    const int*   mk = (const int*)d_in[3];
    float* o = (float*)d_out;
    dim3 grid(SDIM / QBLK, 2 * HNUM);
    attn64<<<grid, NTHR, 0, stream>>>(q, k, v, mk, o);
}

// Round 2
// 77.422 us; speedup vs baseline: 1.3120x; 1.3120x over previous
//
#include <hip/hip_runtime.h>
#include <hip/hip_bf16.h>

#define SDIM 2048
#define DDIM 64
#define HNUM 8
#define QBLK 64
#define KVBLK 64
#define NTHR 256
#define NT (SDIM / KVBLK)
#define LDP 72
#define NEGV -1.0e9f
#define LOG2E 1.44269504088896f

// d_ws layout (bytes): swizzled bf16 images, 16 MiB total.
#define WS_KH 0u
#define WS_KL 4194304u
#define WS_VH 8388608u
#define WS_VL 12582912u

typedef __bf16 bf16x8 __attribute__((ext_vector_type(8)));
typedef float f32x4 __attribute__((ext_vector_type(4)));
typedef unsigned short u16;
typedef u16 u16x4 __attribute__((ext_vector_type(4)));
typedef u16 u16x8 __attribute__((ext_vector_type(8)));

__device__ __forceinline__ u16 f2bf(float f) {
    unsigned u = __float_as_uint(f);
    u += 0x7FFFu + ((u >> 16) & 1u);
    return (u16)(u >> 16);
}
__device__ __forceinline__ float bf2f(u16 h) {
    return __uint_as_float((unsigned)h << 16);
}

union U8 { u16 u[8]; u16x8 v; bf16x8 b; };
union U4 { u16 u[4]; u16x4 v; };

// global -> LDS direct DMA (dest = wave-uniform base + lane*size)
#define GLD16(g, l) __builtin_amdgcn_global_load_lds( \
    (const __attribute__((address_space(1))) unsigned int*)(g), \
    (__attribute__((address_space(3))) unsigned int*)(l), 16, 0, 0)
#define GLD4(g, l) __builtin_amdgcn_global_load_lds( \
    (const __attribute__((address_space(1))) unsigned int*)(g), \
    (__attribute__((address_space(3))) unsigned int*)(l), 4, 0, 0)

// ---------------- prep: fp32 K,V -> swizzled bf16 hi/lo K and V^T tiles ----------------
// K image:  [bh][kv 2048] rows of 128B; element (kv,d) at row*128 + ((2d) ^ ((kv&7)<<4))
// Vt image: [bh][kt 32] blocks of 8KB; (d,kv) at d*128 + ((2*kvl) ^ ((d&7)<<4))
__global__ __launch_bounds__(NTHR)
void attn_prep(const float* __restrict__ K, const float* __restrict__ V,
               char* __restrict__ ws) {
    __shared__ float sT[64][68];
    const int t = threadIdx.x;
    const int kt = blockIdx.x, bh = blockIdx.y;
    const int kv0 = kt * KVBLK;
    const size_t base = (size_t)bh * SDIM * DDIM;
    const int r = t >> 2, c16 = (t & 3) * 16;
    const int sw = (r & 7) << 4;

    // ---- K rows (no transpose) ----
    {
        const float* kp = K + base + (size_t)(kv0 + r) * DDIM + c16;
        char* khrow = ws + WS_KH + ((size_t)bh * SDIM + kv0 + r) * 128;
        char* klrow = ws + WS_KL + ((size_t)bh * SDIM + kv0 + r) * 128;
        #pragma unroll
        for (int j = 0; j < 2; ++j) {
            const float4 a = *(const float4*)(kp + 8 * j);
            const float4 c = *(const float4*)(kp + 8 * j + 4);
            float f[8] = {a.x, a.y, a.z, a.w, c.x, c.y, c.z, c.w};
            U8 h, l;
            #pragma unroll
            for (int e = 0; e < 8; ++e) {
                u16 hh = f2bf(f[e]);
                h.u[e] = hh;
                l.u[e] = f2bf(f[e] - bf2f(hh));
            }
            const int col = (2 * c16 + 16 * j) ^ sw;
            *(u16x8*)(khrow + col) = h.v;
            *(u16x8*)(klrow + col) = l.v;
        }
    }
    // ---- V tile into LDS, then transposed swizzled rows ----
    {
        const float* vp = V + base + (size_t)(kv0 + r) * DDIM + c16;
        #pragma unroll
        for (int j = 0; j < 4; ++j)
            *(float4*)&sT[r][c16 + 4 * j] = *(const float4*)(vp + 4 * j);
    }
    __syncthreads();
    {
        char* vhrow = ws + WS_VH + ((size_t)(bh * NT + kt) * 64 + r) * 128;
        char* vlrow = ws + WS_VL + ((size_t)(bh * NT + kt) * 64 + r) * 128;
        #pragma unroll
        for (int j2 = 0; j2 < 2; ++j2) {
            U8 h, l;
            #pragma unroll
            for (int e = 0; e < 8; ++e) {
                float f = sT[c16 + 8 * j2 + e][r];   // V[kv][d=r] -> Vt[r][kv]
                u16 hh = f2bf(f);
                h.u[e] = hh;
                l.u[e] = f2bf(f - bf2f(hh));
            }
            const int col = (2 * c16 + 16 * j2) ^ sw;
            *(u16x8*)(vhrow + col) = h.v;
            *(u16x8*)(vlrow + col) = l.v;
        }
    }
}

// ---------------- main attention kernel ----------------
__global__ __launch_bounds__(NTHR, 2)
void attn_main(const float* __restrict__ Q, const int* __restrict__ MK,
               const char* __restrict__ ws, float* __restrict__ O) {
    __shared__ __align__(16) u16 sK[2][2][KVBLK * DDIM];  // [buf][hi/lo] 32KB
    __shared__ __align__(16) u16 sV[2][DDIM * KVBLK];     // [hi/lo]      16KB
    __shared__ __align__(16) u16 sP[QBLK][LDP];           // 9216B
    __shared__ __align__(16) int sM[2][KVBLK];            // 512B

    const int tid = threadIdx.x;
    const int wv = tid >> 6, ln = tid & 63;
    const int g = ln >> 4, mi = ln & 15;
    const int bh = blockIdx.y, b = bh >> 3;
    const size_t base = (size_t)bh * SDIM * DDIM;
    const int qrow = blockIdx.x * QBLK + 16 * wv + mi;

    // swizzled per-lane fragment byte-columns (same for K and Vt reads)
    const int sw = (mi & 7) << 4;
    const int c0 = (16 * g) ^ sw;        // k-slice 0 (elems 8g..8g+7)
    const int c1 = (64 + 16 * g) ^ sw;   // k-slice 1 (elems 32+8g..)

    // ---- Q fragments, hi/lo, scaled by (1/8)*log2(e) for exp2-domain softmax ----
    bf16x8 qhi[2], qlo[2];
    {
        const float* qp = Q + base + (size_t)qrow * DDIM;
        #pragma unroll
        for (int ks = 0; ks < 2; ++ks) {
            const float4 a = *(const float4*)(qp + 32 * ks + 8 * g);
            const float4 c = *(const float4*)(qp + 32 * ks + 8 * g + 4);
            float f[8] = {a.x, a.y, a.z, a.w, c.x, c.y, c.z, c.w};
            U8 h, l;
            #pragma unroll
            for (int e = 0; e < 8; ++e) {
                float fs = f[e] * (0.125f * LOG2E);
                u16 hh = f2bf(fs);
                h.u[e] = hh;
                l.u[e] = f2bf(fs - bf2f(hh));
            }
            qhi[ks] = h.b;
            qlo[ks] = l.b;
        }
    }

    const char* kgl = ws + WS_KH + (size_t)bh * SDIM * 128;      // +WS_KL-WS_KH for lo
    const char* vgl = ws + WS_VH + (size_t)bh * NT * 8192;       // per-tile 8KB blocks
    const int* mrow = MK + (size_t)b * SDIM;
    const int chunk = wv * 2;   // this wave's 1KB-chunk base within an 8KB block

    f32x4 zero4 = {0.f, 0.f, 0.f, 0.f};
    f32x4 oacc[4];
    #pragma unroll
    for (int i = 0; i < 4; ++i) oacc[i] = zero4;
    float mrun = -INFINITY, lrun = 0.f;

    // prologue: stage K+mask for tile 0 into buf 0  (5 vmem/wave)
    {
        const char* src = kgl;
        char* dsth = (char*)&sK[0][0][0];
        #pragma unroll
        for (int p = 0; p < 2; ++p) {
            const int off = (chunk + p) * 1024;
            GLD16(src + off + ln * 16, dsth + off);
            GLD16(src + (WS_KL - WS_KH) + off + ln * 16, dsth + 8192 + off);
        }
        GLD4(mrow + ln, &sM[0][0]);
    }

    int cur = 0;
    for (int kt = 0; kt < NT; ++kt) {
        // ---- stage V(kt) into single V buffer (4 vmem) ----
        {
            const char* src = vgl + (size_t)kt * 8192;
            char* dst = (char*)&sV[0][0];
            #pragma unroll
            for (int p = 0; p < 2; ++p) {
                const int off = (chunk + p) * 1024;
                GLD16(src + off + ln * 16, dst + off);
                GLD16(src + (WS_VL - WS_VH) + off + ln * 16, dst + 8192 + off);
            }
        }
        // ---- stage K+mask for next tile (5 vmem) ----
        {
            const int kn = (kt + 1) & (NT - 1);
            const char* src = kgl + (size_t)kn * 8192;
            char* dsth = (char*)&sK[0][0][0] + (cur ^ 1) * 16384;
            #pragma unroll
            for (int p = 0; p < 2; ++p) {
                const int off = (chunk + p) * 1024;
                GLD16(src + off + ln * 16, dsth + off);
                GLD16(src + (WS_KL - WS_KH) + off + ln * 16, dsth + 8192 + off);
            }
            GLD4(mrow + kn * KVBLK + ln, &sM[cur ^ 1][0]);
        }
        // wait current K+mask (oldest 5); leave V(4) + next K/mask(5) in flight
        asm volatile("s_waitcnt vmcnt(9)" ::: "memory");
        __builtin_amdgcn_s_barrier();

        // ---- S^T = K · Q^T ----
        const char* kb = (const char*)&sK[0][0][0] + cur * 16384 + mi * 128;
        float s[4][4];
        #pragma unroll
        for (int mt = 0; mt < 4; ++mt) {
            f32x4 acc = zero4;
            const bf16x8 ah0 = *(const bf16x8*)(kb + mt * 2048 + c0);
            const bf16x8 al0 = *(const bf16x8*)(kb + 8192 + mt * 2048 + c0);
            const bf16x8 ah1 = *(const bf16x8*)(kb + mt * 2048 + c1);
            const bf16x8 al1 = *(const bf16x8*)(kb + 8192 + mt * 2048 + c1);
            acc = __builtin_amdgcn_mfma_f32_16x16x32_bf16(ah0, qhi[0], acc, 0, 0, 0);
            acc = __builtin_amdgcn_mfma_f32_16x16x32_bf16(al0, qhi[0], acc, 0, 0, 0);
            acc = __builtin_amdgcn_mfma_f32_16x16x32_bf16(ah0, qlo[0], acc, 0, 0, 0);
            acc = __builtin_amdgcn_mfma_f32_16x16x32_bf16(ah1, qhi[1], acc, 0, 0, 0);
            acc = __builtin_amdgcn_mfma_f32_16x16x32_bf16(al1, qhi[1], acc, 0, 0, 0);
            acc = __builtin_amdgcn_mfma_f32_16x16x32_bf16(ah1, qlo[1], acc, 0, 0, 0);
            const int4 mk = *(const int4*)&sM[cur][16 * mt + 4 * g];
            s[mt][0] = mk.x ? acc[0] : NEGV;
            s[mt][1] = mk.y ? acc[1] : NEGV;
            s[mt][2] = mk.z ? acc[2] : NEGV;
            s[mt][3] = mk.w ? acc[3] : NEGV;
        }

        // ---- online softmax (exp2 domain) ----
        float tm = s[0][0];
        #pragma unroll
        for (int mt = 0; mt < 4; ++mt)
            #pragma unroll
            for (int r = 0; r < 4; ++r) tm = fmaxf(tm, s[mt][r]);
        tm = fmaxf(tm, __shfl_xor(tm, 16));
        tm = fmaxf(tm, __shfl_xor(tm, 32));
        const float mnew = fmaxf(mrun, tm);
        const float corr = __builtin_amdgcn_exp2f(mrun - mnew);
        mrun = mnew;
        lrun *= corr;
        #pragma unroll
        for (int mt = 0; mt < 4; ++mt) {
            oacc[mt][0] *= corr; oacc[mt][1] *= corr;
            oacc[mt][2] *= corr; oacc[mt][3] *= corr;
        }
        #pragma unroll
        for (int mt = 0; mt < 4; ++mt) {
            U4 pw;
            #pragma unroll
            for (int r = 0; r < 4; ++r) {
                float p = __builtin_amdgcn_exp2f(s[mt][r] - mnew);
                u16 pb = f2bf(p);
                pw.u[r] = pb;
                lrun += bf2f(pb);
            }
            *(u16x4*)&sP[16 * wv + mi][16 * mt + 4 * g] = pw.v;
        }

        // wait V (next 4 oldest done; leave next-tile K/mask 5 in flight)
        asm volatile("s_waitcnt vmcnt(5)" ::: "memory");
        __builtin_amdgcn_s_barrier();

        // ---- O^T += V^T · P^T ----
        const char* vb = (const char*)&sV[0][0] + mi * 128;
        const bf16x8 pf0 = *(const bf16x8*)&sP[16 * wv + mi][8 * g];
        const bf16x8 pf1 = *(const bf16x8*)&sP[16 * wv + mi][32 + 8 * g];
        #pragma unroll
        for (int mt = 0; mt < 4; ++mt) {
            const bf16x8 vh0 = *(const bf16x8*)(vb + mt * 2048 + c0);
            const bf16x8 vl0 = *(const bf16x8*)(vb + 8192 + mt * 2048 + c0);
            const bf16x8 vh1 = *(const bf16x8*)(vb + mt * 2048 + c1);
            const bf16x8 vl1 = *(const bf16x8*)(vb + 8192 + mt * 2048 + c1);
            oacc[mt] = __builtin_amdgcn_mfma_f32_16x16x32_bf16(vh0, pf0, oacc[mt], 0, 0, 0);
            oacc[mt] = __builtin_amdgcn_mfma_f32_16x16x32_bf16(vl0, pf0, oacc[mt], 0, 0, 0);
            oacc[mt] = __builtin_amdgcn_mfma_f32_16x16x32_bf16(vh1, pf1, oacc[mt], 0, 0, 0);
            oacc[mt] = __builtin_amdgcn_mfma_f32_16x16x32_bf16(vl1, pf1, oacc[mt], 0, 0, 0);
        }
        // readers done: next iter may overwrite sV / sP / sK[cur]
        __builtin_amdgcn_s_barrier();
        cur ^= 1;
    }

    // ---- finalize ----
    lrun += __shfl_xor(lrun, 16);
    lrun += __shfl_xor(lrun, 32);
    const float inv = 1.0f / lrun;
    float* op = O + base + (size_t)qrow * DDIM;
    #pragma unroll
    for (int mt = 0; mt < 4; ++mt) {
        float4 o;
        o.x = oacc[mt][0] * inv;
        o.y = oacc[mt][1] * inv;
        o.z = oacc[mt][2] * inv;
        o.w = oacc[mt][3] * inv;
        *(float4*)(op + 16 * mt + 4 * g) = o;
    }
}

extern "C" void kernel_launch(void* const* d_in, const int* in_sizes, int n_in,
                              void* d_out, int out_size, void* d_ws, size_t ws_size,
                              hipStream_t stream) {
    const float* q  = (const float*)d_in[0];
    const float* k  = (const float*)d_in[1];
    const float* v  = (const float*)d_in[2];
    const int*   mk = (const int*)d_in[3];
    float* o = (float*)d_out;
    char* ws = (char*)d_ws;   // needs 16 MiB

    dim3 pgrid(NT, 2 * HNUM);
    attn_prep<<<pgrid, NTHR, 0, stream>>>(k, v, ws);

    dim3 grid(SDIM / QBLK, 2 * HNUM);
    attn_main<<<grid, NTHR, 0, stream>>>(q, mk, ws, o);
}

// Round 3
// 58.563 us; speedup vs baseline: 1.7346x; 1.3220x over previous
//
#include <hip/hip_runtime.h>
#include <hip/hip_bf16.h>

#define SDIM 2048
#define DDIM 64
#define HNUM 8
#define QBLK 64
#define KVBLK 64
#define NTHR 256
#define NT (SDIM / KVBLK)
#define LDP 72
#define NEGV -1.0e9f
#define LOG2E 1.44269504088896f

// d_ws layout (bytes): swizzled bf16 images, 8 MiB total.
#define WS_KH 0u
#define WS_VH 4194304u

typedef __bf16 bf16x8 __attribute__((ext_vector_type(8)));
typedef __bf16 bf16x4 __attribute__((ext_vector_type(4)));
typedef float f32x4 __attribute__((ext_vector_type(4)));
typedef unsigned short u16;
typedef u16 u16x8 __attribute__((ext_vector_type(8)));

__device__ __forceinline__ u16 f2bf(float f) {
    unsigned u = __float_as_uint(f);
    u += 0x7FFFu + ((u >> 16) & 1u);
    return (u16)(u >> 16);
}
__device__ __forceinline__ float bf2f(u16 h) {
    return __uint_as_float((unsigned)h << 16);
}

union U8 { u16 u[8]; u16x8 v; bf16x8 b; };

// global -> LDS direct DMA (dest = wave-uniform base + lane*size)
#define GLD16(g, l) __builtin_amdgcn_global_load_lds( \
    (const __attribute__((address_space(1))) unsigned int*)(g), \
    (__attribute__((address_space(3))) unsigned int*)(l), 16, 0, 0)
#define GLD4(g, l) __builtin_amdgcn_global_load_lds( \
    (const __attribute__((address_space(1))) unsigned int*)(g), \
    (__attribute__((address_space(3))) unsigned int*)(l), 4, 0, 0)

// ---------------- prep: fp32 K,V -> swizzled bf16 K rows and V^T tiles ----------------
// K image:  [bh][kv 2048] rows of 128B; element (kv,d) at row*128 + ((2d) ^ ((kv&7)<<4))
// Vt image: [bh][kt 32] blocks of 8KB; (d,kv) at d*128 + ((2*kvl) ^ ((d&7)<<4))
__global__ __launch_bounds__(NTHR)
void attn_prep(const float* __restrict__ K, const float* __restrict__ V,
               char* __restrict__ ws) {
    __shared__ float sT[64][68];
    const int t = threadIdx.x;
    const int kt = blockIdx.x, bh = blockIdx.y;
    const int kv0 = kt * KVBLK;
    const size_t base = (size_t)bh * SDIM * DDIM;
    const int r = t >> 2, c16 = (t & 3) * 16;
    const int sw = (r & 7) << 4;

    // ---- K rows (no transpose) ----
    {
        const float* kp = K + base + (size_t)(kv0 + r) * DDIM + c16;
        char* khrow = ws + WS_KH + ((size_t)bh * SDIM + kv0 + r) * 128;
        #pragma unroll
        for (int j = 0; j < 2; ++j) {
            const float4 a = *(const float4*)(kp + 8 * j);
            const float4 c = *(const float4*)(kp + 8 * j + 4);
            float f[8] = {a.x, a.y, a.z, a.w, c.x, c.y, c.z, c.w};
            U8 h;
            #pragma unroll
            for (int e = 0; e < 8; ++e) h.u[e] = f2bf(f[e]);
            *(u16x8*)(khrow + ((2 * c16 + 16 * j) ^ sw)) = h.v;
        }
    }
    // ---- V tile into LDS, then transposed swizzled rows ----
    {
        const float* vp = V + base + (size_t)(kv0 + r) * DDIM + c16;
        #pragma unroll
        for (int j = 0; j < 4; ++j)
            *(float4*)&sT[r][c16 + 4 * j] = *(const float4*)(vp + 4 * j);
    }
    __syncthreads();
    {
        char* vhrow = ws + WS_VH + ((size_t)(bh * NT + kt) * 64 + r) * 128;
        #pragma unroll
        for (int j2 = 0; j2 < 2; ++j2) {
            U8 h;
            #pragma unroll
            for (int e = 0; e < 8; ++e)
                h.u[e] = f2bf(sT[c16 + 8 * j2 + e][r]);   // V[kv][d=r] -> Vt[r][kv]
            *(u16x8*)(vhrow + ((2 * c16 + 16 * j2) ^ sw)) = h.v;
        }
    }
}

// ---------------- main attention kernel ----------------
__global__ __launch_bounds__(NTHR, 2)
void attn_main(const float* __restrict__ Q, const int* __restrict__ MK,
               const char* __restrict__ ws, float* __restrict__ O) {
    __shared__ __align__(16) u16 sK[2][KVBLK * DDIM];  // 2 bufs, 16KB
    __shared__ __align__(16) u16 sV[DDIM * KVBLK];     // 8KB
    __shared__ __align__(16) u16 sP[QBLK][LDP];        // 9216B
    __shared__ __align__(16) int sM[2][KVBLK];         // 512B

    const int tid = threadIdx.x;
    const int wv = tid >> 6, ln = tid & 63;
    const int g = ln >> 4, mi = ln & 15;
    const int bh = blockIdx.y, b = bh >> 3;
    const size_t base = (size_t)bh * SDIM * DDIM;
    const int qrow = blockIdx.x * QBLK + 16 * wv + mi;

    // swizzled per-lane fragment byte-columns (same pattern for K and Vt reads)
    const int sw = (mi & 7) << 4;
    const int c0 = (16 * g) ^ sw;        // k-slice 0 (elems 8g..8g+7)
    const int c1 = (64 + 16 * g) ^ sw;   // k-slice 1 (elems 32+8g..)

    // ---- Q fragments, hi/lo, scaled by (1/8)*log2(e) for exp2-domain softmax ----
    bf16x8 qhi[2], qlo[2];
    {
        const float* qp = Q + base + (size_t)qrow * DDIM;
        #pragma unroll
        for (int ks = 0; ks < 2; ++ks) {
            const float4 a = *(const float4*)(qp + 32 * ks + 8 * g);
            const float4 c = *(const float4*)(qp + 32 * ks + 8 * g + 4);
            float f[8] = {a.x, a.y, a.z, a.w, c.x, c.y, c.z, c.w};
            U8 h, l;
            #pragma unroll
            for (int e = 0; e < 8; ++e) {
                float fs = f[e] * (0.125f * LOG2E);
                u16 hh = f2bf(fs);
                h.u[e] = hh;
                l.u[e] = f2bf(fs - bf2f(hh));
            }
            qhi[ks] = h.b;
            qlo[ks] = l.b;
        }
    }

    const char* kgl = ws + WS_KH + (size_t)bh * SDIM * 128;
    const char* vgl = ws + WS_VH + (size_t)bh * NT * 8192;
    const int* mrow = MK + (size_t)b * SDIM;
    const int chunk = wv * 2;   // this wave's 1KB-chunk base within an 8KB tile

    f32x4 zero4 = {0.f, 0.f, 0.f, 0.f};
    f32x4 oacc[4];
    #pragma unroll
    for (int i = 0; i < 4; ++i) oacc[i] = zero4;
    float mrun = -INFINITY, lrun = 0.f;

    // prologue: stage K+mask for tile 0 into buf 0  (3 vmem/wave)
    {
        #pragma unroll
        for (int p = 0; p < 2; ++p) {
            const int off = (chunk + p) * 1024;
            GLD16(kgl + off + ln * 16, (char*)&sK[0][0] + off);
        }
        GLD4(mrow + ln, &sM[0][0]);
    }

    int cur = 0;
    for (int kt = 0; kt < NT; ++kt) {
        // ---- stage V(kt) (2 vmem) ----
        {
            const char* src = vgl + (size_t)kt * 8192;
            #pragma unroll
            for (int p = 0; p < 2; ++p) {
                const int off = (chunk + p) * 1024;
                GLD16(src + off + ln * 16, (char*)&sV[0] + off);
            }
        }
        // ---- stage K+mask for next tile (3 vmem) ----
        {
            const int kn = (kt + 1) & (NT - 1);
            const char* src = kgl + (size_t)kn * 8192;
            char* dst = (char*)&sK[cur ^ 1][0];
            #pragma unroll
            for (int p = 0; p < 2; ++p) {
                const int off = (chunk + p) * 1024;
                GLD16(src + off + ln * 16, dst + off);
            }
            GLD4(mrow + kn * KVBLK + ln, &sM[cur ^ 1][0]);
        }
        // wait current K+mask (oldest 3); leave V(2) + next K/mask(3) in flight
        asm volatile("s_waitcnt vmcnt(5)" ::: "memory");
        __builtin_amdgcn_s_barrier();

        // ---- S^T = K · Q^T ----
        const char* kb = (const char*)&sK[cur][0] + mi * 128;
        float s[4][4];
        #pragma unroll
        for (int mt = 0; mt < 4; ++mt) {
            f32x4 acc = zero4;
            const bf16x8 ah0 = *(const bf16x8*)(kb + mt * 2048 + c0);
            const bf16x8 ah1 = *(const bf16x8*)(kb + mt * 2048 + c1);
            acc = __builtin_amdgcn_mfma_f32_16x16x32_bf16(ah0, qhi[0], acc, 0, 0, 0);
            acc = __builtin_amdgcn_mfma_f32_16x16x32_bf16(ah0, qlo[0], acc, 0, 0, 0);
            acc = __builtin_amdgcn_mfma_f32_16x16x32_bf16(ah1, qhi[1], acc, 0, 0, 0);
            acc = __builtin_amdgcn_mfma_f32_16x16x32_bf16(ah1, qlo[1], acc, 0, 0, 0);
            const int4 mk = *(const int4*)&sM[cur][16 * mt + 4 * g];
            s[mt][0] = mk.x ? acc[0] : NEGV;
            s[mt][1] = mk.y ? acc[1] : NEGV;
            s[mt][2] = mk.z ? acc[2] : NEGV;
            s[mt][3] = mk.w ? acc[3] : NEGV;
        }

        // ---- online softmax (exp2 domain, defer-rescale THR=8) ----
        float tm = s[0][0];
        #pragma unroll
        for (int mt = 0; mt < 4; ++mt)
            #pragma unroll
            for (int r = 0; r < 4; ++r) tm = fmaxf(tm, s[mt][r]);
        tm = fmaxf(tm, __shfl_xor(tm, 16));
        tm = fmaxf(tm, __shfl_xor(tm, 32));
        if (__any(tm > mrun + 8.f)) {
            const float mnew = fmaxf(mrun, tm);
            const float corr = __builtin_amdgcn_exp2f(mrun - mnew);
            mrun = mnew;
            lrun *= corr;
            #pragma unroll
            for (int mt = 0; mt < 4; ++mt) {
                oacc[mt][0] *= corr; oacc[mt][1] *= corr;
                oacc[mt][2] *= corr; oacc[mt][3] *= corr;
            }
        }
        #pragma unroll
        for (int mt = 0; mt < 4; ++mt) {
            bf16x4 pw;
            #pragma unroll
            for (int r = 0; r < 4; ++r) {
                const float p = __builtin_amdgcn_exp2f(s[mt][r] - mrun);
                pw[r] = (__bf16)p;   // native cvt (RNE)
                lrun += p;
            }
            *(bf16x4*)&sP[16 * wv + mi][16 * mt + 4 * g] = pw;
        }

        // wait V (leave next-tile K/mask 3 in flight)
        asm volatile("s_waitcnt vmcnt(3)" ::: "memory");
        __builtin_amdgcn_s_barrier();

        // ---- O^T += V^T · P^T ----
        const char* vb = (const char*)&sV[0] + mi * 128;
        const bf16x8 pf0 = *(const bf16x8*)&sP[16 * wv + mi][8 * g];
        const bf16x8 pf1 = *(const bf16x8*)&sP[16 * wv + mi][32 + 8 * g];
        #pragma unroll
        for (int mt = 0; mt < 4; ++mt) {
            const bf16x8 vh0 = *(const bf16x8*)(vb + mt * 2048 + c0);
            const bf16x8 vh1 = *(const bf16x8*)(vb + mt * 2048 + c1);
            oacc[mt] = __builtin_amdgcn_mfma_f32_16x16x32_bf16(vh0, pf0, oacc[mt], 0, 0, 0);
            oacc[mt] = __builtin_amdgcn_mfma_f32_16x16x32_bf16(vh1, pf1, oacc[mt], 0, 0, 0);
        }
        // readers done: next iter may overwrite sV / sP / sK[cur]
        __builtin_amdgcn_s_barrier();
        cur ^= 1;
    }

    // ---- finalize ----
    lrun += __shfl_xor(lrun, 16);
    lrun += __shfl_xor(lrun, 32);
    const float inv = 1.0f / lrun;
    float* op = O + base + (size_t)qrow * DDIM;
    #pragma unroll
    for (int mt = 0; mt < 4; ++mt) {
        float4 o;
        o.x = oacc[mt][0] * inv;
        o.y = oacc[mt][1] * inv;
        o.z = oacc[mt][2] * inv;
        o.w = oacc[mt][3] * inv;
        *(float4*)(op + 16 * mt + 4 * g) = o;
    }
}

extern "C" void kernel_launch(void* const* d_in, const int* in_sizes, int n_in,
                              void* d_out, int out_size, void* d_ws, size_t ws_size,
                              hipStream_t stream) {
    const float* q  = (const float*)d_in[0];
    const float* k  = (const float*)d_in[1];
    const float* v  = (const float*)d_in[2];
    const int*   mk = (const int*)d_in[3];
    float* o = (float*)d_out;
    char* ws = (char*)d_ws;   // needs 8 MiB

    dim3 pgrid(NT, 2 * HNUM);
    attn_prep<<<pgrid, NTHR, 0, stream>>>(k, v, ws);

    dim3 grid(SDIM / QBLK, 2 * HNUM);
    attn_main<<<grid, NTHR, 0, stream>>>(q, mk, ws, o);
}

// Round 4
// 53.769 us; speedup vs baseline: 1.8892x; 1.0892x over previous
//
#include <hip/hip_runtime.h>
#include <hip/hip_bf16.h>

#define SDIM 2048
#define DDIM 64
#define HNUM 8
#define QBLK 64
#define KVBLK 64
#define NTHR 256
#define NT (SDIM / KVBLK)
#define NSPLIT 2
#define TPS (NT / NSPLIT)          // tiles per split = 16
#define LDP 72
#define NEGV -1.0e9f
#define LOG2E 1.44269504088896f

// d_ws layout (bytes), 13.1 MiB total:
#define WS_KH 0u                   // K bf16 swizzled rows, 4 MiB
#define WS_VH 4194304u             // V^T bf16 swizzled tiles, 4 MiB
#define WS_O1 8388608u             // split-1 normalized partial O, bf16, 4 MiB
#define WS_ML 12582912u            // (m,l) float2 per [split][bh][row], 512 KiB

typedef __bf16 bf16x8 __attribute__((ext_vector_type(8)));
typedef __bf16 bf16x4 __attribute__((ext_vector_type(4)));
typedef float f32x4 __attribute__((ext_vector_type(4)));
typedef unsigned short u16;
typedef u16 u16x4 __attribute__((ext_vector_type(4)));
typedef u16 u16x8 __attribute__((ext_vector_type(8)));

__device__ __forceinline__ u16 f2bf(float f) {
    unsigned u = __float_as_uint(f);
    u += 0x7FFFu + ((u >> 16) & 1u);
    return (u16)(u >> 16);
}
__device__ __forceinline__ float bf2f(u16 h) {
    return __uint_as_float((unsigned)h << 16);
}

union U8 { u16 u[8]; u16x8 v; bf16x8 b; };

#define GLD16(g, l) __builtin_amdgcn_global_load_lds( \
    (const __attribute__((address_space(1))) unsigned int*)(g), \
    (__attribute__((address_space(3))) unsigned int*)(l), 16, 0, 0)
#define GLD4(g, l) __builtin_amdgcn_global_load_lds( \
    (const __attribute__((address_space(1))) unsigned int*)(g), \
    (__attribute__((address_space(3))) unsigned int*)(l), 4, 0, 0)

// ---------------- prep: fp32 K,V -> swizzled bf16 K rows and V^T tiles ----------------
__global__ __launch_bounds__(NTHR)
void attn_prep(const float* __restrict__ K, const float* __restrict__ V,
               char* __restrict__ ws) {
    __shared__ float sT[64][68];
    const int t = threadIdx.x;
    const int kt = blockIdx.x, bh = blockIdx.y;
    const int kv0 = kt * KVBLK;
    const size_t base = (size_t)bh * SDIM * DDIM;
    const int r = t >> 2, c16 = (t & 3) * 16;
    const int sw = (r & 7) << 4;

    {
        const float* kp = K + base + (size_t)(kv0 + r) * DDIM + c16;
        char* khrow = ws + WS_KH + ((size_t)bh * SDIM + kv0 + r) * 128;
        #pragma unroll
        for (int j = 0; j < 2; ++j) {
            const float4 a = *(const float4*)(kp + 8 * j);
            const float4 c = *(const float4*)(kp + 8 * j + 4);
            float f[8] = {a.x, a.y, a.z, a.w, c.x, c.y, c.z, c.w};
            U8 h;
            #pragma unroll
            for (int e = 0; e < 8; ++e) h.u[e] = f2bf(f[e]);
            *(u16x8*)(khrow + ((2 * c16 + 16 * j) ^ sw)) = h.v;
        }
    }
    {
        const float* vp = V + base + (size_t)(kv0 + r) * DDIM + c16;
        #pragma unroll
        for (int j = 0; j < 4; ++j)
            *(float4*)&sT[r][c16 + 4 * j] = *(const float4*)(vp + 4 * j);
    }
    __syncthreads();
    {
        char* vhrow = ws + WS_VH + ((size_t)(bh * NT + kt) * 64 + r) * 128;
        #pragma unroll
        for (int j2 = 0; j2 < 2; ++j2) {
            U8 h;
            #pragma unroll
            for (int e = 0; e < 8; ++e)
                h.u[e] = f2bf(sT[c16 + 8 * j2 + e][r]);
            *(u16x8*)(vhrow + ((2 * c16 + 16 * j2) ^ sw)) = h.v;
        }
    }
}

// ---------------- main attention kernel (kv-split via blockIdx.z) ----------------
__global__ __launch_bounds__(NTHR, 4)
void attn_main(const float* __restrict__ Q, const int* __restrict__ MK,
               char* __restrict__ ws, float* __restrict__ O) {
    __shared__ __align__(16) u16 sK[2][KVBLK * DDIM];  // 16KB
    __shared__ __align__(16) u16 sV[DDIM * KVBLK];     // 8KB
    __shared__ __align__(16) u16 sP[QBLK][LDP];        // 9216B
    __shared__ __align__(16) int sM[2][KVBLK];         // 512B

    const int tid = threadIdx.x;
    const int wv = tid >> 6, ln = tid & 63;
    const int g = ln >> 4, mi = ln & 15;
    const int bh = blockIdx.y, b = bh >> 3;
    const int split = blockIdx.z;
    const int kt0 = split * TPS;
    const size_t base = (size_t)bh * SDIM * DDIM;
    const int qrow = blockIdx.x * QBLK + 16 * wv + mi;

    const int sw = (mi & 7) << 4;
    const int c0 = (16 * g) ^ sw;
    const int c1 = (64 + 16 * g) ^ sw;

    // ---- Q fragments, hi/lo, scaled by (1/8)*log2(e) ----
    bf16x8 qhi[2], qlo[2];
    {
        const float* qp = Q + base + (size_t)qrow * DDIM;
        #pragma unroll
        for (int ks = 0; ks < 2; ++ks) {
            const float4 a = *(const float4*)(qp + 32 * ks + 8 * g);
            const float4 c = *(const float4*)(qp + 32 * ks + 8 * g + 4);
            float f[8] = {a.x, a.y, a.z, a.w, c.x, c.y, c.z, c.w};
            U8 h, l;
            #pragma unroll
            for (int e = 0; e < 8; ++e) {
                float fs = f[e] * (0.125f * LOG2E);
                u16 hh = f2bf(fs);
                h.u[e] = hh;
                l.u[e] = f2bf(fs - bf2f(hh));
            }
            qhi[ks] = h.b;
            qlo[ks] = l.b;
        }
    }

    const char* kgl = ws + WS_KH + (size_t)bh * SDIM * 128;
    const char* vgl = ws + WS_VH + (size_t)bh * NT * 8192;
    const int* mrow = MK + (size_t)b * SDIM;
    const int chunk = wv * 2;

    f32x4 zero4 = {0.f, 0.f, 0.f, 0.f};
    f32x4 oacc[4];
    #pragma unroll
    for (int i = 0; i < 4; ++i) oacc[i] = zero4;
    float mrun = -INFINITY, lrun = 0.f;

    // prologue: stage K+mask for first tile of this split
    {
        const char* src = kgl + (size_t)kt0 * 8192;
        #pragma unroll
        for (int p = 0; p < 2; ++p) {
            const int off = (chunk + p) * 1024;
            GLD16(src + off + ln * 16, (char*)&sK[0][0] + off);
        }
        GLD4(mrow + kt0 * KVBLK + ln, &sM[0][0]);
    }

    int cur = 0;
    for (int i = 0; i < TPS; ++i) {
        const int kt = kt0 + i;
        // ---- stage V(kt) ----
        {
            const char* src = vgl + (size_t)kt * 8192;
            #pragma unroll
            for (int p = 0; p < 2; ++p) {
                const int off = (chunk + p) * 1024;
                GLD16(src + off + ln * 16, (char*)&sV[0] + off);
            }
        }
        // ---- stage K+mask for next tile (wrap within split) ----
        {
            const int kn = kt0 + ((i + 1) & (TPS - 1));
            const char* src = kgl + (size_t)kn * 8192;
            char* dst = (char*)&sK[cur ^ 1][0];
            #pragma unroll
            for (int p = 0; p < 2; ++p) {
                const int off = (chunk + p) * 1024;
                GLD16(src + off + ln * 16, dst + off);
            }
            GLD4(mrow + kn * KVBLK + ln, &sM[cur ^ 1][0]);
        }
        asm volatile("s_waitcnt vmcnt(5)" ::: "memory");
        __builtin_amdgcn_s_barrier();

        // ---- S^T = K · Q^T ----
        const char* kb = (const char*)&sK[cur][0] + mi * 128;
        float s[4][4];
        #pragma unroll
        for (int mt = 0; mt < 4; ++mt) {
            f32x4 acc = zero4;
            const bf16x8 ah0 = *(const bf16x8*)(kb + mt * 2048 + c0);
            const bf16x8 ah1 = *(const bf16x8*)(kb + mt * 2048 + c1);
            acc = __builtin_amdgcn_mfma_f32_16x16x32_bf16(ah0, qhi[0], acc, 0, 0, 0);
            acc = __builtin_amdgcn_mfma_f32_16x16x32_bf16(ah0, qlo[0], acc, 0, 0, 0);
            acc = __builtin_amdgcn_mfma_f32_16x16x32_bf16(ah1, qhi[1], acc, 0, 0, 0);
            acc = __builtin_amdgcn_mfma_f32_16x16x32_bf16(ah1, qlo[1], acc, 0, 0, 0);
            const int4 mk = *(const int4*)&sM[cur][16 * mt + 4 * g];
            s[mt][0] = mk.x ? acc[0] : NEGV;
            s[mt][1] = mk.y ? acc[1] : NEGV;
            s[mt][2] = mk.z ? acc[2] : NEGV;
            s[mt][3] = mk.w ? acc[3] : NEGV;
        }

        // ---- online softmax (exp2 domain, defer-rescale THR=8) ----
        float tm = fmaxf(fmaxf(s[0][0], s[0][1]), s[0][2]);
        tm = fmaxf(fmaxf(tm, s[0][3]), s[1][0]);
        tm = fmaxf(fmaxf(tm, s[1][1]), s[1][2]);
        tm = fmaxf(fmaxf(tm, s[1][3]), s[2][0]);
        tm = fmaxf(fmaxf(tm, s[2][1]), s[2][2]);
        tm = fmaxf(fmaxf(tm, s[2][3]), s[3][0]);
        tm = fmaxf(fmaxf(tm, s[3][1]), s[3][2]);
        tm = fmaxf(tm, s[3][3]);
        tm = fmaxf(tm, __shfl_xor(tm, 16));
        tm = fmaxf(tm, __shfl_xor(tm, 32));
        if (__any(tm > mrun + 8.f)) {
            const float mnew = fmaxf(mrun, tm);
            const float corr = __builtin_amdgcn_exp2f(mrun - mnew);
            mrun = mnew;
            lrun *= corr;
            #pragma unroll
            for (int mt = 0; mt < 4; ++mt) {
                oacc[mt][0] *= corr; oacc[mt][1] *= corr;
                oacc[mt][2] *= corr; oacc[mt][3] *= corr;
            }
        }
        #pragma unroll
        for (int mt = 0; mt < 4; ++mt) {
            bf16x4 pw;
            #pragma unroll
            for (int r = 0; r < 4; ++r) {
                const float p = __builtin_amdgcn_exp2f(s[mt][r] - mrun);
                pw[r] = (__bf16)p;
                lrun += p;
            }
            *(bf16x4*)&sP[16 * wv + mi][16 * mt + 4 * g] = pw;
        }

        asm volatile("s_waitcnt vmcnt(3)" ::: "memory");
        __builtin_amdgcn_s_barrier();

        // ---- O^T += V^T · P^T ----
        const char* vb = (const char*)&sV[0] + mi * 128;
        const bf16x8 pf0 = *(const bf16x8*)&sP[16 * wv + mi][8 * g];
        const bf16x8 pf1 = *(const bf16x8*)&sP[16 * wv + mi][32 + 8 * g];
        #pragma unroll
        for (int mt = 0; mt < 4; ++mt) {
            const bf16x8 vh0 = *(const bf16x8*)(vb + mt * 2048 + c0);
            const bf16x8 vh1 = *(const bf16x8*)(vb + mt * 2048 + c1);
            oacc[mt] = __builtin_amdgcn_mfma_f32_16x16x32_bf16(vh0, pf0, oacc[mt], 0, 0, 0);
            oacc[mt] = __builtin_amdgcn_mfma_f32_16x16x32_bf16(vh1, pf1, oacc[mt], 0, 0, 0);
        }
        __builtin_amdgcn_s_barrier();
        cur ^= 1;
    }

    // ---- finalize: normalized partial + (m,l) ----
    lrun += __shfl_xor(lrun, 16);
    lrun += __shfl_xor(lrun, 32);
    const float inv = 1.0f / lrun;
    if (split == 0) {
        float* op = O + base + (size_t)qrow * DDIM;
        #pragma unroll
        for (int mt = 0; mt < 4; ++mt) {
            float4 o;
            o.x = oacc[mt][0] * inv;
            o.y = oacc[mt][1] * inv;
            o.z = oacc[mt][2] * inv;
            o.w = oacc[mt][3] * inv;
            *(float4*)(op + 16 * mt + 4 * g) = o;
        }
    } else {
        u16* op1 = (u16*)(ws + WS_O1) + ((size_t)bh * SDIM + qrow) * DDIM;
        #pragma unroll
        for (int mt = 0; mt < 4; ++mt) {
            u16x4 o;
            #pragma unroll
            for (int r = 0; r < 4; ++r) o[r] = f2bf(oacc[mt][r] * inv);
            *(u16x4*)(op1 + 16 * mt + 4 * g) = o;
        }
    }
    if (g == 0) {
        float2* mlp = (float2*)(ws + WS_ML) + ((size_t)(split * 2 * HNUM + bh) * SDIM + qrow);
        *mlp = make_float2(mrun, lrun);
    }
}

// ---------------- combine: O = (w0*O0 + w1*O1) / (w0+w1) ----------------
__global__ __launch_bounds__(NTHR)
void attn_combine(const char* __restrict__ ws, float* __restrict__ O) {
    const int t = threadIdx.x;
    const size_t grow = (size_t)blockIdx.x * 16 + (t >> 4);   // global row over [bh][qrow]
    const int e4 = (t & 15) * 4;
    const float2* ml = (const float2*)(ws + WS_ML);
    const float2 a = ml[grow];
    const float2 bml = ml[(size_t)2 * HNUM * SDIM + grow];
    const float m = fmaxf(a.x, bml.x);
    float w0 = a.y * __builtin_amdgcn_exp2f(a.x - m);
    float w1 = bml.y * __builtin_amdgcn_exp2f(bml.x - m);
    const float inv = 1.0f / (w0 + w1);
    w0 *= inv; w1 *= inv;
    float* op = O + grow * DDIM + e4;
    const float4 o0 = *(const float4*)op;
    const u16x4 o1 = *(const u16x4*)((const u16*)(ws + WS_O1) + grow * DDIM + e4);
    float4 r;
    r.x = o0.x * w0 + bf2f(o1[0]) * w1;
    r.y = o0.y * w0 + bf2f(o1[1]) * w1;
    r.z = o0.z * w0 + bf2f(o1[2]) * w1;
    r.w = o0.w * w0 + bf2f(o1[3]) * w1;
    *(float4*)op = r;
}

extern "C" void kernel_launch(void* const* d_in, const int* in_sizes, int n_in,
                              void* d_out, int out_size, void* d_ws, size_t ws_size,
                              hipStream_t stream) {
    const float* q  = (const float*)d_in[0];
    const float* k  = (const float*)d_in[1];
    const float* v  = (const float*)d_in[2];
    const int*   mk = (const int*)d_in[3];
    float* o = (float*)d_out;
    char* ws = (char*)d_ws;   // needs 13.1 MiB

    dim3 pgrid(NT, 2 * HNUM);
    attn_prep<<<pgrid, NTHR, 0, stream>>>(k, v, ws);

    dim3 grid(SDIM / QBLK, 2 * HNUM, NSPLIT);
    attn_main<<<grid, NTHR, 0, stream>>>(q, mk, ws, o);

    dim3 cgrid((2 * HNUM * SDIM) / 16);
    attn_combine<<<cgrid, NTHR, 0, stream>>>(ws, o);
}

// Round 5
// 53.157 us; speedup vs baseline: 1.9109x; 1.0115x over previous
//
#include <hip/hip_runtime.h>
#include <hip/hip_bf16.h>

#define SDIM 2048
#define DDIM 64
#define HNUM 8
#define QBLK 64
#define KVBLK 64
#define NTHR 256
#define NT (SDIM / KVBLK)
#define NSPLIT 2
#define LDP 72
#define NEGV -1.0e9f
#define LOG2E 1.44269504088896f

// d_ws layout (bytes), ~13.2 MiB total:
#define WS_KH 0u                   // compacted K bf16 swizzled rows, 4 MiB
#define WS_VH 4194304u             // compacted V^T bf16 swizzled tiles, 4 MiB
#define WS_O1 8388608u             // split-1 normalized partial O, bf16, 4 MiB
#define WS_ML 12582912u            // (m,l) float2 per [split][bh][row], 512 KiB
#define WS_IDX 13107200u           // compacted orig indices int32 [b][2048], 16 KiB
#define WS_VM 13123584u            // valid flags int32 [b][2048], 16 KiB
#define WS_CNT 13139968u           // counts int32 [b], 8 B

typedef __bf16 bf16x8 __attribute__((ext_vector_type(8)));
typedef __bf16 bf16x4 __attribute__((ext_vector_type(4)));
typedef float f32x4 __attribute__((ext_vector_type(4)));
typedef unsigned short u16;
typedef u16 u16x4 __attribute__((ext_vector_type(4)));
typedef u16 u16x8 __attribute__((ext_vector_type(8)));

__device__ __forceinline__ u16 f2bf(float f) {
    unsigned u = __float_as_uint(f);
    u += 0x7FFFu + ((u >> 16) & 1u);
    return (u16)(u >> 16);
}
__device__ __forceinline__ float bf2f(u16 h) {
    return __uint_as_float((unsigned)h << 16);
}

union U8 { u16 u[8]; u16x8 v; bf16x8 b; };

#define GLD16(g, l) __builtin_amdgcn_global_load_lds( \
    (const __attribute__((address_space(1))) unsigned int*)(g), \
    (__attribute__((address_space(3))) unsigned int*)(l), 16, 0, 0)
#define GLD4(g, l) __builtin_amdgcn_global_load_lds( \
    (const __attribute__((address_space(1))) unsigned int*)(g), \
    (__attribute__((address_space(3))) unsigned int*)(l), 4, 0, 0)

// ---------------- scan: compact unmasked key indices (1 wave per batch) ----------------
__global__ __launch_bounds__(64)
void attn_scan(const int* __restrict__ MK, char* __restrict__ ws) {
    const int b = blockIdx.x, ln = threadIdx.x;
    const int* m = MK + (size_t)b * SDIM;
    int* idx = (int*)(ws + WS_IDX) + b * SDIM;
    int* vm  = (int*)(ws + WS_VM) + b * SDIM;
    int base = 0;
    for (int c = 0; c < SDIM; c += 64) {
        const int mm = m[c + ln];
        const unsigned long long bal = __ballot(mm != 0);
        const int pre = __popcll(bal & ((1ULL << ln) - 1ULL));
        if (mm) idx[base + pre] = c + ln;
        base += (int)__popcll(bal);
    }
    if (ln == 0) ((int*)(ws + WS_CNT))[b] = base;
    for (int j = ln; j < SDIM; j += 64) {
        vm[j] = (j < base) ? 1 : 0;
        if (j >= base) idx[j] = 0;   // safe gather target for tail padding
    }
}

// ---------------- prep: gather-compact fp32 K,V -> swizzled bf16 K rows, V^T tiles ----
// K image:  [bh][slot 2048] rows of 128B; (slot,d) at slot*128 + ((2d) ^ ((slot&7)<<4))
// Vt image: [bh][kt 32] blocks of 8KB; (d,kvl) at d*128 + ((2*kvl) ^ ((d&7)<<4))
__global__ __launch_bounds__(NTHR)
void attn_prep(const float* __restrict__ K, const float* __restrict__ V,
               char* __restrict__ ws) {
    __shared__ float sT[64][68];
    const int t = threadIdx.x;
    const int kt = blockIdx.x, bh = blockIdx.y;
    const int kv0 = kt * KVBLK;
    const size_t base = (size_t)bh * SDIM * DDIM;
    const int r = t >> 2, c16 = (t & 3) * 16;
    const int sw = (r & 7) << 4;
    const int orig = ((const int*)(ws + WS_IDX))[(bh >> 3) * SDIM + kv0 + r];

    {
        const float* kp = K + base + (size_t)orig * DDIM + c16;
        char* khrow = ws + WS_KH + ((size_t)bh * SDIM + kv0 + r) * 128;
        #pragma unroll
        for (int j = 0; j < 2; ++j) {
            const float4 a = *(const float4*)(kp + 8 * j);
            const float4 c = *(const float4*)(kp + 8 * j + 4);
            float f[8] = {a.x, a.y, a.z, a.w, c.x, c.y, c.z, c.w};
            U8 h;
            #pragma unroll
            for (int e = 0; e < 8; ++e) h.u[e] = f2bf(f[e]);
            *(u16x8*)(khrow + ((2 * c16 + 16 * j) ^ sw)) = h.v;
        }
    }
    {
        const float* vp = V + base + (size_t)orig * DDIM + c16;
        #pragma unroll
        for (int j = 0; j < 4; ++j)
            *(float4*)&sT[r][c16 + 4 * j] = *(const float4*)(vp + 4 * j);
    }
    __syncthreads();
    {
        char* vhrow = ws + WS_VH + ((size_t)(bh * NT + kt) * 64 + r) * 128;
        #pragma unroll
        for (int j2 = 0; j2 < 2; ++j2) {
            U8 h;
            #pragma unroll
            for (int e = 0; e < 8; ++e)
                h.u[e] = f2bf(sT[c16 + 8 * j2 + e][r]);
            *(u16x8*)(vhrow + ((2 * c16 + 16 * j2) ^ sw)) = h.v;
        }
    }
}

// ---------------- main attention kernel (compacted keys, kv-split) ----------------
__global__ __launch_bounds__(NTHR, 4)
void attn_main(const float* __restrict__ Q, char* __restrict__ ws,
               float* __restrict__ O) {
    __shared__ __align__(16) u16 sK[2][KVBLK * DDIM];  // 16KB
    __shared__ __align__(16) u16 sV[DDIM * KVBLK];     // 8KB
    __shared__ __align__(16) u16 sP[QBLK][LDP];        // 9216B
    __shared__ __align__(16) int sM[2][KVBLK];         // 512B

    const int tid = threadIdx.x;
    const int wv = tid >> 6, ln = tid & 63;
    const int g = ln >> 4, mi = ln & 15;
    const int bh = blockIdx.y, b = bh >> 3;
    const int split = blockIdx.z;
    const size_t base = (size_t)bh * SDIM * DDIM;
    const int qrow = blockIdx.x * QBLK + 16 * wv + mi;

    const int L = ((const int*)(ws + WS_CNT))[b];
    const int nt = (L + KVBLK - 1) >> 6;
    const int half = (nt + 1) >> 1;
    const int t0 = split ? half : 0;
    const int tn = split ? nt : half;

    const int sw = (mi & 7) << 4;
    const int c0 = (16 * g) ^ sw;
    const int c1 = (64 + 16 * g) ^ sw;

    // ---- Q fragments, hi/lo, scaled by (1/8)*log2(e) ----
    bf16x8 qhi[2], qlo[2];
    {
        const float* qp = Q + base + (size_t)qrow * DDIM;
        #pragma unroll
        for (int ks = 0; ks < 2; ++ks) {
            const float4 a = *(const float4*)(qp + 32 * ks + 8 * g);
            const float4 c = *(const float4*)(qp + 32 * ks + 8 * g + 4);
            float f[8] = {a.x, a.y, a.z, a.w, c.x, c.y, c.z, c.w};
            U8 h, l;
            #pragma unroll
            for (int e = 0; e < 8; ++e) {
                float fs = f[e] * (0.125f * LOG2E);
                u16 hh = f2bf(fs);
                h.u[e] = hh;
                l.u[e] = f2bf(fs - bf2f(hh));
            }
            qhi[ks] = h.b;
            qlo[ks] = l.b;
        }
    }

    const char* kgl = ws + WS_KH + (size_t)bh * SDIM * 128;
    const char* vgl = ws + WS_VH + (size_t)bh * NT * 8192;
    const int* mrow = (const int*)(ws + WS_VM) + b * SDIM;
    const int chunk = wv * 2;

    f32x4 zero4 = {0.f, 0.f, 0.f, 0.f};
    f32x4 oacc[4];
    #pragma unroll
    for (int i = 0; i < 4; ++i) oacc[i] = zero4;
    float mrun = -INFINITY, lrun = 0.f;

    if (t0 < tn) {
        // prologue: stage K+valid for first tile of this split
        {
            const char* src = kgl + (size_t)t0 * 8192;
            #pragma unroll
            for (int p = 0; p < 2; ++p) {
                const int off = (chunk + p) * 1024;
                GLD16(src + off + ln * 16, (char*)&sK[0][0] + off);
            }
            GLD4(mrow + t0 * KVBLK + ln, &sM[0][0]);
        }

        int cur = 0;
        for (int kt = t0; kt < tn; ++kt) {
            // ---- stage V(kt) ----
            {
                const char* src = vgl + (size_t)kt * 8192;
                #pragma unroll
                for (int p = 0; p < 2; ++p) {
                    const int off = (chunk + p) * 1024;
                    GLD16(src + off + ln * 16, (char*)&sV[0] + off);
                }
            }
            // ---- stage K+valid for next tile (wrap within split) ----
            {
                const int kn = (kt + 1 < tn) ? kt + 1 : t0;
                const char* src = kgl + (size_t)kn * 8192;
                char* dst = (char*)&sK[cur ^ 1][0];
                #pragma unroll
                for (int p = 0; p < 2; ++p) {
                    const int off = (chunk + p) * 1024;
                    GLD16(src + off + ln * 16, dst + off);
                }
                GLD4(mrow + kn * KVBLK + ln, &sM[cur ^ 1][0]);
            }
            asm volatile("s_waitcnt vmcnt(5)" ::: "memory");
            __builtin_amdgcn_s_barrier();

            // ---- S^T = K · Q^T ----
            const char* kb = (const char*)&sK[cur][0] + mi * 128;
            float s[4][4];
            #pragma unroll
            for (int mt = 0; mt < 4; ++mt) {
                f32x4 acc = zero4;
                const bf16x8 ah0 = *(const bf16x8*)(kb + mt * 2048 + c0);
                const bf16x8 ah1 = *(const bf16x8*)(kb + mt * 2048 + c1);
                acc = __builtin_amdgcn_mfma_f32_16x16x32_bf16(ah0, qhi[0], acc, 0, 0, 0);
                acc = __builtin_amdgcn_mfma_f32_16x16x32_bf16(ah0, qlo[0], acc, 0, 0, 0);
                acc = __builtin_amdgcn_mfma_f32_16x16x32_bf16(ah1, qhi[1], acc, 0, 0, 0);
                acc = __builtin_amdgcn_mfma_f32_16x16x32_bf16(ah1, qlo[1], acc, 0, 0, 0);
                const int4 mk = *(const int4*)&sM[cur][16 * mt + 4 * g];
                s[mt][0] = mk.x ? acc[0] : NEGV;
                s[mt][1] = mk.y ? acc[1] : NEGV;
                s[mt][2] = mk.z ? acc[2] : NEGV;
                s[mt][3] = mk.w ? acc[3] : NEGV;
            }

            // ---- online softmax (exp2 domain, defer-rescale THR=8) ----
            float tm = fmaxf(fmaxf(s[0][0], s[0][1]), s[0][2]);
            tm = fmaxf(fmaxf(tm, s[0][3]), s[1][0]);
            tm = fmaxf(fmaxf(tm, s[1][1]), s[1][2]);
            tm = fmaxf(fmaxf(tm, s[1][3]), s[2][0]);
            tm = fmaxf(fmaxf(tm, s[2][1]), s[2][2]);
            tm = fmaxf(fmaxf(tm, s[2][3]), s[3][0]);
            tm = fmaxf(fmaxf(tm, s[3][1]), s[3][2]);
            tm = fmaxf(tm, s[3][3]);
            tm = fmaxf(tm, __shfl_xor(tm, 16));
            tm = fmaxf(tm, __shfl_xor(tm, 32));
            if (__any(tm > mrun + 8.f)) {
                const float mnew = fmaxf(mrun, tm);
                const float corr = __builtin_amdgcn_exp2f(mrun - mnew);
                mrun = mnew;
                lrun *= corr;
                #pragma unroll
                for (int mt = 0; mt < 4; ++mt) {
                    oacc[mt][0] *= corr; oacc[mt][1] *= corr;
                    oacc[mt][2] *= corr; oacc[mt][3] *= corr;
                }
            }
            #pragma unroll
            for (int mt = 0; mt < 4; ++mt) {
                bf16x4 pw;
                #pragma unroll
                for (int r = 0; r < 4; ++r) {
                    const float p = __builtin_amdgcn_exp2f(s[mt][r] - mrun);
                    pw[r] = (__bf16)p;
                    lrun += p;
                }
                *(bf16x4*)&sP[16 * wv + mi][16 * mt + 4 * g] = pw;
            }

            asm volatile("s_waitcnt vmcnt(3)" ::: "memory");
            __builtin_amdgcn_s_barrier();

            // ---- O^T += V^T · P^T ----
            const char* vb = (const char*)&sV[0] + mi * 128;
            const bf16x8 pf0 = *(const bf16x8*)&sP[16 * wv + mi][8 * g];
            const bf16x8 pf1 = *(const bf16x8*)&sP[16 * wv + mi][32 + 8 * g];
            #pragma unroll
            for (int mt = 0; mt < 4; ++mt) {
                const bf16x8 vh0 = *(const bf16x8*)(vb + mt * 2048 + c0);
                const bf16x8 vh1 = *(const bf16x8*)(vb + mt * 2048 + c1);
                oacc[mt] = __builtin_amdgcn_mfma_f32_16x16x32_bf16(vh0, pf0, oacc[mt], 0, 0, 0);
                oacc[mt] = __builtin_amdgcn_mfma_f32_16x16x32_bf16(vh1, pf1, oacc[mt], 0, 0, 0);
            }
            __builtin_amdgcn_s_barrier();
            cur ^= 1;
        }
    }

    // ---- finalize: normalized partial + (m,l) ----
    lrun += __shfl_xor(lrun, 16);
    lrun += __shfl_xor(lrun, 32);
    const float inv = lrun > 0.f ? 1.0f / lrun : 0.f;
    if (split == 0) {
        float* op = O + base + (size_t)qrow * DDIM;
        #pragma unroll
        for (int mt = 0; mt < 4; ++mt) {
            float4 o;
            o.x = oacc[mt][0] * inv;
            o.y = oacc[mt][1] * inv;
            o.z = oacc[mt][2] * inv;
            o.w = oacc[mt][3] * inv;
            *(float4*)(op + 16 * mt + 4 * g) = o;
        }
    } else {
        u16* op1 = (u16*)(ws + WS_O1) + ((size_t)bh * SDIM + qrow) * DDIM;
        #pragma unroll
        for (int mt = 0; mt < 4; ++mt) {
            u16x4 o;
            #pragma unroll
            for (int r = 0; r < 4; ++r) o[r] = f2bf(oacc[mt][r] * inv);
            *(u16x4*)(op1 + 16 * mt + 4 * g) = o;
        }
    }
    if (g == 0) {
        float2* mlp = (float2*)(ws + WS_ML) + ((size_t)(split * 2 * HNUM + bh) * SDIM + qrow);
        *mlp = make_float2(mrun, lrun);
    }
}

// ---------------- combine: O = (w0*O0 + w1*O1) / (w0+w1) ----------------
__global__ __launch_bounds__(NTHR)
void attn_combine(const char* __restrict__ ws, float* __restrict__ O) {
    const int t = threadIdx.x;
    const size_t grow = (size_t)blockIdx.x * 16 + (t >> 4);
    const int e4 = (t & 15) * 4;
    const float2* ml = (const float2*)(ws + WS_ML);
    const float2 a = ml[grow];
    const float2 bml = ml[(size_t)2 * HNUM * SDIM + grow];
    const float m = fmaxf(a.x, bml.x);
    float w0 = (a.y > 0.f) ? a.y * __builtin_amdgcn_exp2f(a.x - m) : 0.f;
    float w1 = (bml.y > 0.f) ? bml.y * __builtin_amdgcn_exp2f(bml.x - m) : 0.f;
    const float sw = w0 + w1;
    const float inv = sw > 0.f ? 1.0f / sw : 0.f;
    w0 *= inv; w1 *= inv;
    float* op = O + grow * DDIM + e4;
    const float4 o0 = *(const float4*)op;
    const u16x4 o1 = *(const u16x4*)((const u16*)(ws + WS_O1) + grow * DDIM + e4);
    float4 r;
    r.x = o0.x * w0 + bf2f(o1[0]) * w1;
    r.y = o0.y * w0 + bf2f(o1[1]) * w1;
    r.z = o0.z * w0 + bf2f(o1[2]) * w1;
    r.w = o0.w * w0 + bf2f(o1[3]) * w1;
    *(float4*)op = r;
}

extern "C" void kernel_launch(void* const* d_in, const int* in_sizes, int n_in,
                              void* d_out, int out_size, void* d_ws, size_t ws_size,
                              hipStream_t stream) {
    const float* q  = (const float*)d_in[0];
    const float* k  = (const float*)d_in[1];
    const float* v  = (const float*)d_in[2];
    const int*   mk = (const int*)d_in[3];
    float* o = (float*)d_out;
    char* ws = (char*)d_ws;   // needs ~13.2 MiB

    attn_scan<<<2, 64, 0, stream>>>(mk, ws);

    dim3 pgrid(NT, 2 * HNUM);
    attn_prep<<<pgrid, NTHR, 0, stream>>>(k, v, ws);

    dim3 grid(SDIM / QBLK, 2 * HNUM, NSPLIT);
    attn_main<<<grid, NTHR, 0, stream>>>(q, ws, o);

    dim3 cgrid((2 * HNUM * SDIM) / 16);
    attn_combine<<<cgrid, NTHR, 0, stream>>>(ws, o);
}

// Round 6
// 44.079 us; speedup vs baseline: 2.3045x; 1.2060x over previous
//
#include <hip/hip_runtime.h>
#include <hip/hip_bf16.h>

#define SDIM 2048
#define DDIM 64
#define HNUM 8
#define QBLK 64
#define KVBLK 64
#define NTHR 256
#define NT (SDIM / KVBLK)
#define NSPLIT 2
#define LDP 72
#define NEGV -1.0e9f
#define LOG2E 1.44269504088896f

// d_ws layout (bytes), ~13.2 MiB total:
#define WS_KH 0u                   // compacted K bf16 swizzled rows, 4 MiB
#define WS_VH 4194304u             // compacted V^T bf16 swizzled tiles, 4 MiB
#define WS_O1 8388608u             // split-1 normalized partial O, bf16, 4 MiB
#define WS_ML 12582912u            // (m,l) float2 per [split][bh][row], 512 KiB
#define WS_IDX 13107200u           // compacted orig indices int32 [b][2048], 16 KiB
#define WS_VM 13123584u            // valid flags int32 [b][2048], 16 KiB
#define WS_CNT 13139968u           // counts int32 [b], 8 B

typedef __bf16 bf16x8 __attribute__((ext_vector_type(8)));
typedef __bf16 bf16x4 __attribute__((ext_vector_type(4)));
typedef float f32x4 __attribute__((ext_vector_type(4)));
typedef unsigned short u16;
typedef u16 u16x4 __attribute__((ext_vector_type(4)));
typedef u16 u16x8 __attribute__((ext_vector_type(8)));

__device__ __forceinline__ u16 f2bf(float f) {
    unsigned u = __float_as_uint(f);
    u += 0x7FFFu + ((u >> 16) & 1u);
    return (u16)(u >> 16);
}
__device__ __forceinline__ float bf2f(u16 h) {
    return __uint_as_float((unsigned)h << 16);
}

union U8 { u16 u[8]; u16x8 v; bf16x8 b; };

#define GLD16(g, l) __builtin_amdgcn_global_load_lds( \
    (const __attribute__((address_space(1))) unsigned int*)(g), \
    (__attribute__((address_space(3))) unsigned int*)(l), 16, 0, 0)
#define GLD4(g, l) __builtin_amdgcn_global_load_lds( \
    (const __attribute__((address_space(1))) unsigned int*)(g), \
    (__attribute__((address_space(3))) unsigned int*)(l), 4, 0, 0)

// ---------------- scan: parallel compaction, 1 block (256 thr) per batch ----------------
__global__ __launch_bounds__(NTHR)
void attn_scan(const int* __restrict__ MK, char* __restrict__ ws) {
    const int b = blockIdx.x, t = threadIdx.x;
    const int ln = t & 63, wv = t >> 6;
    const int* m = MK + (size_t)b * SDIM;
    int* idx = (int*)(ws + WS_IDX) + b * SDIM;
    int* vm  = (int*)(ws + WS_VM) + b * SDIM;

    int vals[8], cnt = 0;
    #pragma unroll
    for (int e = 0; e < 8; ++e) {
        vals[e] = m[t * 8 + e];
        cnt += (vals[e] != 0);
    }
    // inclusive scan of cnt within wave
    int inc = cnt;
    #pragma unroll
    for (int off = 1; off < 64; off <<= 1) {
        int n = __shfl_up(inc, off);
        if (ln >= off) inc += n;
    }
    __shared__ int wtot[4];
    if (ln == 63) wtot[wv] = inc;
    __syncthreads();
    int wbase = 0;
    #pragma unroll
    for (int w = 0; w < 4; ++w) if (w < wv) wbase += wtot[w];
    const int total = wtot[0] + wtot[1] + wtot[2] + wtot[3];
    int pos = wbase + inc - cnt;   // exclusive prefix
    #pragma unroll
    for (int e = 0; e < 8; ++e)
        if (vals[e]) idx[pos++] = t * 8 + e;
    if (t == 0) ((int*)(ws + WS_CNT))[b] = total;
    #pragma unroll
    for (int e = 0; e < 8; ++e) {
        const int j = t * 8 + e;
        vm[j] = (j < total) ? 1 : 0;
        if (j >= total) idx[j] = 0;   // safe gather target for tail padding
    }
}

// ---------------- prep: gather-compact fp32 K,V -> swizzled bf16 K rows, V^T tiles ----
__global__ __launch_bounds__(NTHR)
void attn_prep(const float* __restrict__ K, const float* __restrict__ V,
               char* __restrict__ ws) {
    __shared__ float sT[64][68];
    const int t = threadIdx.x;
    const int kt = blockIdx.x, bh = blockIdx.y;
    const int kv0 = kt * KVBLK;
    const int cnt = ((const int*)(ws + WS_CNT))[bh >> 3];
    if (kv0 >= ((cnt + KVBLK - 1) & ~(KVBLK - 1))) return;   // tile fully past tail
    const size_t base = (size_t)bh * SDIM * DDIM;
    const int r = t >> 2, c16 = (t & 3) * 16;
    const int sw = (r & 7) << 4;
    const int orig = ((const int*)(ws + WS_IDX))[(bh >> 3) * SDIM + kv0 + r];

    {
        const float* kp = K + base + (size_t)orig * DDIM + c16;
        char* khrow = ws + WS_KH + ((size_t)bh * SDIM + kv0 + r) * 128;
        #pragma unroll
        for (int j = 0; j < 2; ++j) {
            const float4 a = *(const float4*)(kp + 8 * j);
            const float4 c = *(const float4*)(kp + 8 * j + 4);
            float f[8] = {a.x, a.y, a.z, a.w, c.x, c.y, c.z, c.w};
            U8 h;
            #pragma unroll
            for (int e = 0; e < 8; ++e) h.u[e] = f2bf(f[e]);
            *(u16x8*)(khrow + ((2 * c16 + 16 * j) ^ sw)) = h.v;
        }
    }
    {
        const float* vp = V + base + (size_t)orig * DDIM + c16;
        #pragma unroll
        for (int j = 0; j < 4; ++j)
            *(float4*)&sT[r][c16 + 4 * j] = *(const float4*)(vp + 4 * j);
    }
    __syncthreads();
    {
        char* vhrow = ws + WS_VH + ((size_t)(bh * NT + kt) * 64 + r) * 128;
        #pragma unroll
        for (int j2 = 0; j2 < 2; ++j2) {
            U8 h;
            #pragma unroll
            for (int e = 0; e < 8; ++e)
                h.u[e] = f2bf(sT[c16 + 8 * j2 + e][r]);
            *(u16x8*)(vhrow + ((2 * c16 + 16 * j2) ^ sw)) = h.v;
        }
    }
}

// ---------------- main attention kernel (compacted keys, kv-split) ----------------
__global__ __launch_bounds__(NTHR, 4)
void attn_main(const float* __restrict__ Q, char* __restrict__ ws,
               float* __restrict__ O) {
    __shared__ __align__(16) u16 sK[2][KVBLK * DDIM];  // 16KB
    __shared__ __align__(16) u16 sV[DDIM * KVBLK];     // 8KB
    __shared__ __align__(16) u16 sP[QBLK][LDP];        // 9216B
    __shared__ __align__(16) int sM[2][KVBLK];         // 512B

    const int tid = threadIdx.x;
    const int wv = tid >> 6, ln = tid & 63;
    const int g = ln >> 4, mi = ln & 15;
    const int bh = blockIdx.y, b = bh >> 3;
    const int split = blockIdx.z;
    const size_t base = (size_t)bh * SDIM * DDIM;
    const int qrow = blockIdx.x * QBLK + 16 * wv + mi;

    const int L = ((const int*)(ws + WS_CNT))[b];
    const int nt = (L + KVBLK - 1) >> 6;
    const int half = (nt + 1) >> 1;
    const int t0 = split ? half : 0;
    const int tn = split ? nt : half;

    const int sw = (mi & 7) << 4;
    const int c0 = (16 * g) ^ sw;
    const int c1 = (64 + 16 * g) ^ sw;

    // ---- Q fragments, hi/lo, scaled by (1/8)*log2(e) ----
    bf16x8 qhi[2], qlo[2];
    {
        const float* qp = Q + base + (size_t)qrow * DDIM;
        #pragma unroll
        for (int ks = 0; ks < 2; ++ks) {
            const float4 a = *(const float4*)(qp + 32 * ks + 8 * g);
            const float4 c = *(const float4*)(qp + 32 * ks + 8 * g + 4);
            float f[8] = {a.x, a.y, a.z, a.w, c.x, c.y, c.z, c.w};
            U8 h, l;
            #pragma unroll
            for (int e = 0; e < 8; ++e) {
                float fs = f[e] * (0.125f * LOG2E);
                u16 hh = f2bf(fs);
                h.u[e] = hh;
                l.u[e] = f2bf(fs - bf2f(hh));
            }
            qhi[ks] = h.b;
            qlo[ks] = l.b;
        }
    }

    const char* kgl = ws + WS_KH + (size_t)bh * SDIM * 128;
    const char* vgl = ws + WS_VH + (size_t)bh * NT * 8192;
    const int* mrow = (const int*)(ws + WS_VM) + b * SDIM;
    const int chunk = wv * 2;

    f32x4 zero4 = {0.f, 0.f, 0.f, 0.f};
    f32x4 oacc[4];
    #pragma unroll
    for (int i = 0; i < 4; ++i) oacc[i] = zero4;
    float mrun = -INFINITY, lrun = 0.f;

    if (t0 < tn) {
        // prologue: stage K+valid for first tile of this split
        {
            const char* src = kgl + (size_t)t0 * 8192;
            #pragma unroll
            for (int p = 0; p < 2; ++p) {
                const int off = (chunk + p) * 1024;
                GLD16(src + off + ln * 16, (char*)&sK[0][0] + off);
            }
            GLD4(mrow + t0 * KVBLK + ln, &sM[0][0]);
        }

        int cur = 0;
        for (int kt = t0; kt < tn; ++kt) {
            // ---- stage V(kt) ----
            {
                const char* src = vgl + (size_t)kt * 8192;
                #pragma unroll
                for (int p = 0; p < 2; ++p) {
                    const int off = (chunk + p) * 1024;
                    GLD16(src + off + ln * 16, (char*)&sV[0] + off);
                }
            }
            // ---- stage K+valid for next tile (wrap within split) ----
            {
                const int kn = (kt + 1 < tn) ? kt + 1 : t0;
                const char* src = kgl + (size_t)kn * 8192;
                char* dst = (char*)&sK[cur ^ 1][0];
                #pragma unroll
                for (int p = 0; p < 2; ++p) {
                    const int off = (chunk + p) * 1024;
                    GLD16(src + off + ln * 16, dst + off);
                }
                GLD4(mrow + kn * KVBLK + ln, &sM[cur ^ 1][0]);
            }
            asm volatile("s_waitcnt vmcnt(5)" ::: "memory");
            __builtin_amdgcn_s_barrier();

            // ---- S^T = K · Q^T ----
            const char* kb = (const char*)&sK[cur][0] + mi * 128;
            float s[4][4];
            #pragma unroll
            for (int mt = 0; mt < 4; ++mt) {
                f32x4 acc = zero4;
                const bf16x8 ah0 = *(const bf16x8*)(kb + mt * 2048 + c0);
                const bf16x8 ah1 = *(const bf16x8*)(kb + mt * 2048 + c1);
                acc = __builtin_amdgcn_mfma_f32_16x16x32_bf16(ah0, qhi[0], acc, 0, 0, 0);
                acc = __builtin_amdgcn_mfma_f32_16x16x32_bf16(ah0, qlo[0], acc, 0, 0, 0);
                acc = __builtin_amdgcn_mfma_f32_16x16x32_bf16(ah1, qhi[1], acc, 0, 0, 0);
                acc = __builtin_amdgcn_mfma_f32_16x16x32_bf16(ah1, qlo[1], acc, 0, 0, 0);
                const int4 mk = *(const int4*)&sM[cur][16 * mt + 4 * g];
                s[mt][0] = mk.x ? acc[0] : NEGV;
                s[mt][1] = mk.y ? acc[1] : NEGV;
                s[mt][2] = mk.z ? acc[2] : NEGV;
                s[mt][3] = mk.w ? acc[3] : NEGV;
            }

            // ---- online softmax (exp2 domain, defer-rescale THR=8) ----
            float tm = fmaxf(fmaxf(s[0][0], s[0][1]), s[0][2]);
            tm = fmaxf(fmaxf(tm, s[0][3]), s[1][0]);
            tm = fmaxf(fmaxf(tm, s[1][1]), s[1][2]);
            tm = fmaxf(fmaxf(tm, s[1][3]), s[2][0]);
            tm = fmaxf(fmaxf(tm, s[2][1]), s[2][2]);
            tm = fmaxf(fmaxf(tm, s[2][3]), s[3][0]);
            tm = fmaxf(fmaxf(tm, s[3][1]), s[3][2]);
            tm = fmaxf(tm, s[3][3]);
            tm = fmaxf(tm, __shfl_xor(tm, 16));
            tm = fmaxf(tm, __shfl_xor(tm, 32));
            if (__any(tm > mrun + 8.f)) {
                const float mnew = fmaxf(mrun, tm);
                const float corr = __builtin_amdgcn_exp2f(mrun - mnew);
                mrun = mnew;
                lrun *= corr;
                #pragma unroll
                for (int mt = 0; mt < 4; ++mt) {
                    oacc[mt][0] *= corr; oacc[mt][1] *= corr;
                    oacc[mt][2] *= corr; oacc[mt][3] *= corr;
                }
            }
            #pragma unroll
            for (int mt = 0; mt < 4; ++mt) {
                bf16x4 pw;
                #pragma unroll
                for (int r = 0; r < 4; ++r) {
                    const float p = __builtin_amdgcn_exp2f(s[mt][r] - mrun);
                    pw[r] = (__bf16)p;
                    lrun += p;
                }
                *(bf16x4*)&sP[16 * wv + mi][16 * mt + 4 * g] = pw;
            }

            asm volatile("s_waitcnt vmcnt(3)" ::: "memory");
            __builtin_amdgcn_s_barrier();

            // ---- O^T += V^T · P^T ----
            const char* vb = (const char*)&sV[0] + mi * 128;
            const bf16x8 pf0 = *(const bf16x8*)&sP[16 * wv + mi][8 * g];
            const bf16x8 pf1 = *(const bf16x8*)&sP[16 * wv + mi][32 + 8 * g];
            #pragma unroll
            for (int mt = 0; mt < 4; ++mt) {
                const bf16x8 vh0 = *(const bf16x8*)(vb + mt * 2048 + c0);
                const bf16x8 vh1 = *(const bf16x8*)(vb + mt * 2048 + c1);
                oacc[mt] = __builtin_amdgcn_mfma_f32_16x16x32_bf16(vh0, pf0, oacc[mt], 0, 0, 0);
                oacc[mt] = __builtin_amdgcn_mfma_f32_16x16x32_bf16(vh1, pf1, oacc[mt], 0, 0, 0);
            }
            __builtin_amdgcn_s_barrier();
            cur ^= 1;
        }
    }

    // ---- finalize: normalized partial + (m,l) ----
    lrun += __shfl_xor(lrun, 16);
    lrun += __shfl_xor(lrun, 32);
    const float inv = lrun > 0.f ? 1.0f / lrun : 0.f;
    if (split == 0) {
        float* op = O + base + (size_t)qrow * DDIM;
        #pragma unroll
        for (int mt = 0; mt < 4; ++mt) {
            float4 o;
            o.x = oacc[mt][0] * inv;
            o.y = oacc[mt][1] * inv;
            o.z = oacc[mt][2] * inv;
            o.w = oacc[mt][3] * inv;
            *(float4*)(op + 16 * mt + 4 * g) = o;
        }
    } else {
        u16* op1 = (u16*)(ws + WS_O1) + ((size_t)bh * SDIM + qrow) * DDIM;
        #pragma unroll
        for (int mt = 0; mt < 4; ++mt) {
            u16x4 o;
            #pragma unroll
            for (int r = 0; r < 4; ++r) o[r] = f2bf(oacc[mt][r] * inv);
            *(u16x4*)(op1 + 16 * mt + 4 * g) = o;
        }
    }
    if (g == 0) {
        float2* mlp = (float2*)(ws + WS_ML) + ((size_t)(split * 2 * HNUM + bh) * SDIM + qrow);
        *mlp = make_float2(mrun, lrun);
    }
}

// ---------------- combine: O = (w0*O0 + w1*O1) / (w0+w1) ----------------
__global__ __launch_bounds__(NTHR)
void attn_combine(const char* __restrict__ ws, float* __restrict__ O) {
    const int t = threadIdx.x;
    const size_t grow = (size_t)blockIdx.x * 16 + (t >> 4);
    const int e4 = (t & 15) * 4;
    const float2* ml = (const float2*)(ws + WS_ML);
    const float2 a = ml[grow];
    const float2 bml = ml[(size_t)2 * HNUM * SDIM + grow];
    const float m = fmaxf(a.x, bml.x);
    float w0 = (a.y > 0.f) ? a.y * __builtin_amdgcn_exp2f(a.x - m) : 0.f;
    float w1 = (bml.y > 0.f) ? bml.y * __builtin_amdgcn_exp2f(bml.x - m) : 0.f;
    const float sw = w0 + w1;
    const float inv = sw > 0.f ? 1.0f / sw : 0.f;
    w0 *= inv; w1 *= inv;
    float* op = O + grow * DDIM + e4;
    const float4 o0 = *(const float4*)op;
    const u16x4 o1 = *(const u16x4*)((const u16*)(ws + WS_O1) + grow * DDIM + e4);
    float4 r;
    r.x = o0.x * w0 + bf2f(o1[0]) * w1;
    r.y = o0.y * w0 + bf2f(o1[1]) * w1;
    r.z = o0.z * w0 + bf2f(o1[2]) * w1;
    r.w = o0.w * w0 + bf2f(o1[3]) * w1;
    *(float4*)op = r;
}

extern "C" void kernel_launch(void* const* d_in, const int* in_sizes, int n_in,
                              void* d_out, int out_size, void* d_ws, size_t ws_size,
                              hipStream_t stream) {
    const float* q  = (const float*)d_in[0];
    const float* k  = (const float*)d_in[1];
    const float* v  = (const float*)d_in[2];
    const int*   mk = (const int*)d_in[3];
    float* o = (float*)d_out;
    char* ws = (char*)d_ws;   // needs ~13.2 MiB

    attn_scan<<<2, NTHR, 0, stream>>>(mk, ws);

    dim3 pgrid(NT, 2 * HNUM);
    attn_prep<<<pgrid, NTHR, 0, stream>>>(k, v, ws);

    dim3 grid(SDIM / QBLK, 2 * HNUM, NSPLIT);
    attn_main<<<grid, NTHR, 0, stream>>>(q, ws, o);

    dim3 cgrid((2 * HNUM * SDIM) / 16);
    attn_combine<<<cgrid, NTHR, 0, stream>>>(ws, o);
}

// Round 7
// 41.144 us; speedup vs baseline: 2.4689x; 1.0713x over previous
//
#include <hip/hip_runtime.h>
#include <hip/hip_bf16.h>

#define SDIM 2048
#define DDIM 64
#define HNUM 8
#define QBLK 64
#define KVBLK 64
#define NTHR 256
#define NT (SDIM / KVBLK)
#define NSPLIT 2
#define LDP 72
#define NEGV -1.0e9f
#define LOG2E 1.44269504088896f
#define FIXMAX 12.0f

// d_ws layout (bytes), ~13.2 MiB total:
#define WS_KH 0u                   // compacted K bf16 swizzled rows, 4 MiB
#define WS_VH 4194304u             // compacted V^T bf16 swizzled tiles, 4 MiB
#define WS_O1 8388608u             // split-1 normalized partial O, bf16, 4 MiB
#define WS_ML 12582912u            // l (float) per [split][bh][row], 256 KiB
#define WS_IDX 13107200u           // compacted orig indices int32 [b][2048], 16 KiB
#define WS_CNT 13123584u           // counts int32 [b], 8 B

typedef __bf16 bf16x8 __attribute__((ext_vector_type(8)));
typedef __bf16 bf16x4 __attribute__((ext_vector_type(4)));
typedef float f32x4 __attribute__((ext_vector_type(4)));
typedef unsigned short u16;
typedef u16 u16x4 __attribute__((ext_vector_type(4)));
typedef u16 u16x8 __attribute__((ext_vector_type(8)));

__device__ __forceinline__ u16 f2bf(float f) {
    unsigned u = __float_as_uint(f);
    u += 0x7FFFu + ((u >> 16) & 1u);
    return (u16)(u >> 16);
}
__device__ __forceinline__ float bf2f(u16 h) {
    return __uint_as_float((unsigned)h << 16);
}

union U8 { u16 u[8]; u16x8 v; bf16x8 b; };

#define GLD16(g, l) __builtin_amdgcn_global_load_lds( \
    (const __attribute__((address_space(1))) unsigned int*)(g), \
    (__attribute__((address_space(3))) unsigned int*)(l), 16, 0, 0)

// ---------------- scan: parallel compaction, 1 block (256 thr) per batch ----------------
__global__ __launch_bounds__(NTHR)
void attn_scan(const int* __restrict__ MK, char* __restrict__ ws) {
    const int b = blockIdx.x, t = threadIdx.x;
    const int ln = t & 63, wv = t >> 6;
    const int* m = MK + (size_t)b * SDIM;
    int* idx = (int*)(ws + WS_IDX) + b * SDIM;

    int vals[8], cnt = 0;
    #pragma unroll
    for (int e = 0; e < 8; ++e) {
        vals[e] = m[t * 8 + e];
        cnt += (vals[e] != 0);
    }
    int inc = cnt;
    #pragma unroll
    for (int off = 1; off < 64; off <<= 1) {
        int n = __shfl_up(inc, off);
        if (ln >= off) inc += n;
    }
    __shared__ int wtot[4];
    if (ln == 63) wtot[wv] = inc;
    __syncthreads();
    int wbase = 0;
    #pragma unroll
    for (int w = 0; w < 4; ++w) if (w < wv) wbase += wtot[w];
    const int total = wtot[0] + wtot[1] + wtot[2] + wtot[3];
    int pos = wbase + inc - cnt;
    #pragma unroll
    for (int e = 0; e < 8; ++e)
        if (vals[e]) idx[pos++] = t * 8 + e;
    if (t == 0) ((int*)(ws + WS_CNT))[b] = total;
    #pragma unroll
    for (int e = 0; e < 8; ++e) {
        const int j = t * 8 + e;
        if (j >= total) idx[j] = 0;   // safe gather target for tail padding
    }
}

// ---------------- prep: gather-compact fp32 K,V -> swizzled bf16 K rows, V^T tiles ----
__global__ __launch_bounds__(NTHR)
void attn_prep(const float* __restrict__ K, const float* __restrict__ V,
               char* __restrict__ ws) {
    __shared__ float sT[64][68];
    const int t = threadIdx.x;
    const int kt = blockIdx.x, bh = blockIdx.y;
    const int kv0 = kt * KVBLK;
    const int cnt = ((const int*)(ws + WS_CNT))[bh >> 3];
    if (kv0 >= ((cnt + KVBLK - 1) & ~(KVBLK - 1))) return;   // tile fully past tail
    const size_t base = (size_t)bh * SDIM * DDIM;
    const int r = t >> 2, c16 = (t & 3) * 16;
    const int sw = (r & 7) << 4;
    const int orig = ((const int*)(ws + WS_IDX))[(bh >> 3) * SDIM + kv0 + r];

    {
        const float* kp = K + base + (size_t)orig * DDIM + c16;
        char* khrow = ws + WS_KH + ((size_t)bh * SDIM + kv0 + r) * 128;
        #pragma unroll
        for (int j = 0; j < 2; ++j) {
            const float4 a = *(const float4*)(kp + 8 * j);
            const float4 c = *(const float4*)(kp + 8 * j + 4);
            float f[8] = {a.x, a.y, a.z, a.w, c.x, c.y, c.z, c.w};
            U8 h;
            #pragma unroll
            for (int e = 0; e < 8; ++e) h.u[e] = f2bf(f[e]);
            *(u16x8*)(khrow + ((2 * c16 + 16 * j) ^ sw)) = h.v;
        }
    }
    {
        const float* vp = V + base + (size_t)orig * DDIM + c16;
        #pragma unroll
        for (int j = 0; j < 4; ++j)
            *(float4*)&sT[r][c16 + 4 * j] = *(const float4*)(vp + 4 * j);
    }
    __syncthreads();
    {
        char* vhrow = ws + WS_VH + ((size_t)(bh * NT + kt) * 64 + r) * 128;
        #pragma unroll
        for (int j2 = 0; j2 < 2; ++j2) {
            U8 h;
            #pragma unroll
            for (int e = 0; e < 8; ++e)
                h.u[e] = f2bf(sT[c16 + 8 * j2 + e][r]);
            *(u16x8*)(vhrow + ((2 * c16 + 16 * j2) ^ sw)) = h.v;
        }
    }
}

// ---------------- main attention kernel (compacted keys, kv-split, fixed-max) --------
__global__ __launch_bounds__(NTHR, 4)
void attn_main(const float* __restrict__ Q, char* __restrict__ ws,
               float* __restrict__ O) {
    __shared__ __align__(16) u16 sK[2][KVBLK * DDIM];  // 16KB
    __shared__ __align__(16) u16 sV[DDIM * KVBLK];     // 8KB
    __shared__ __align__(16) u16 sP[QBLK][LDP];        // 9216B

    const int tid = threadIdx.x;
    const int wv = tid >> 6, ln = tid & 63;
    const int g = ln >> 4, mi = ln & 15;
    const int bh = blockIdx.y, b = bh >> 3;
    const int split = blockIdx.z;
    const size_t base = (size_t)bh * SDIM * DDIM;
    const int qrow = blockIdx.x * QBLK + 16 * wv + mi;

    const int L = ((const int*)(ws + WS_CNT))[b];
    const int nt = (L + KVBLK - 1) >> 6;
    const int half = (nt + 1) >> 1;
    const int t0 = split ? half : 0;
    const int tn = split ? nt : half;

    const int sw = (mi & 7) << 4;
    const int c0 = (16 * g) ^ sw;
    const int c1 = (64 + 16 * g) ^ sw;

    // ---- Q fragments, hi/lo, scaled by (1/8)*log2(e) ----
    bf16x8 qhi[2], qlo[2];
    {
        const float* qp = Q + base + (size_t)qrow * DDIM;
        #pragma unroll
        for (int ks = 0; ks < 2; ++ks) {
            const float4 a = *(const float4*)(qp + 32 * ks + 8 * g);
            const float4 c = *(const float4*)(qp + 32 * ks + 8 * g + 4);
            float f[8] = {a.x, a.y, a.z, a.w, c.x, c.y, c.z, c.w};
            U8 h, l;
            #pragma unroll
            for (int e = 0; e < 8; ++e) {
                float fs = f[e] * (0.125f * LOG2E);
                u16 hh = f2bf(fs);
                h.u[e] = hh;
                l.u[e] = f2bf(fs - bf2f(hh));
            }
            qhi[ks] = h.b;
            qlo[ks] = l.b;
        }
    }

    const char* kgl = ws + WS_KH + (size_t)bh * SDIM * 128;
    const char* vgl = ws + WS_VH + (size_t)bh * NT * 8192;
    const int chunk = wv * 2;

    f32x4 zero4 = {0.f, 0.f, 0.f, 0.f};
    f32x4 oacc[4];
    #pragma unroll
    for (int i = 0; i < 4; ++i) oacc[i] = zero4;
    float lrun = 0.f;

    if (t0 < tn) {
        // prologue: stage K for first tile of this split (2 vmem)
        {
            const char* src = kgl + (size_t)t0 * 8192;
            #pragma unroll
            for (int p = 0; p < 2; ++p) {
                const int off = (chunk + p) * 1024;
                GLD16(src + off + ln * 16, (char*)&sK[0][0] + off);
            }
        }

        int cur = 0;
        for (int kt = t0; kt < tn; ++kt) {
            // ---- stage V(kt) (2 vmem) ----
            {
                const char* src = vgl + (size_t)kt * 8192;
                #pragma unroll
                for (int p = 0; p < 2; ++p) {
                    const int off = (chunk + p) * 1024;
                    GLD16(src + off + ln * 16, (char*)&sV[0] + off);
                }
            }
            // ---- stage K for next tile (2 vmem) ----
            {
                const int kn = (kt + 1 < tn) ? kt + 1 : t0;
                const char* src = kgl + (size_t)kn * 8192;
                char* dst = (char*)&sK[cur ^ 1][0];
                #pragma unroll
                for (int p = 0; p < 2; ++p) {
                    const int off = (chunk + p) * 1024;
                    GLD16(src + off + ln * 16, dst + off);
                }
            }
            // wait current K (oldest 2); leave V(2) + next K(2) in flight
            asm volatile("s_waitcnt vmcnt(4)" ::: "memory");
            __builtin_amdgcn_s_barrier();

            // ---- S^T = K · Q^T ----
            const char* kb = (const char*)&sK[cur][0] + mi * 128;
            float s[4][4];
            #pragma unroll
            for (int mt = 0; mt < 4; ++mt) {
                f32x4 acc = zero4;
                const bf16x8 ah0 = *(const bf16x8*)(kb + mt * 2048 + c0);
                const bf16x8 ah1 = *(const bf16x8*)(kb + mt * 2048 + c1);
                acc = __builtin_amdgcn_mfma_f32_16x16x32_bf16(ah0, qhi[0], acc, 0, 0, 0);
                acc = __builtin_amdgcn_mfma_f32_16x16x32_bf16(ah0, qlo[0], acc, 0, 0, 0);
                acc = __builtin_amdgcn_mfma_f32_16x16x32_bf16(ah1, qhi[1], acc, 0, 0, 0);
                acc = __builtin_amdgcn_mfma_f32_16x16x32_bf16(ah1, qlo[1], acc, 0, 0, 0);
                s[mt][0] = acc[0]; s[mt][1] = acc[1];
                s[mt][2] = acc[2]; s[mt][3] = acc[3];
            }
            // arithmetic tail masking (wave-uniform branch; full tiles skip)
            const int rem = L - kt * KVBLK;
            if (rem < KVBLK) {
                #pragma unroll
                for (int mt = 0; mt < 4; ++mt)
                    #pragma unroll
                    for (int r = 0; r < 4; ++r)
                        if (16 * mt + 4 * g + r >= rem) s[mt][r] = NEGV;
            }

            // ---- softmax, fixed max (no cross-lane, no rescale) ----
            #pragma unroll
            for (int mt = 0; mt < 4; ++mt) {
                bf16x4 pw;
                #pragma unroll
                for (int r = 0; r < 4; ++r) {
                    const float p = __builtin_amdgcn_exp2f(s[mt][r] - FIXMAX);
                    pw[r] = (__bf16)p;
                    lrun += p;
                }
                *(bf16x4*)&sP[16 * wv + mi][16 * mt + 4 * g] = pw;
            }

            // wait V (leave next-tile K 2 in flight)
            asm volatile("s_waitcnt vmcnt(2)" ::: "memory");
            __builtin_amdgcn_s_barrier();

            // ---- O^T += V^T · P^T ----
            const char* vb = (const char*)&sV[0] + mi * 128;
            const bf16x8 pf0 = *(const bf16x8*)&sP[16 * wv + mi][8 * g];
            const bf16x8 pf1 = *(const bf16x8*)&sP[16 * wv + mi][32 + 8 * g];
            #pragma unroll
            for (int mt = 0; mt < 4; ++mt) {
                const bf16x8 vh0 = *(const bf16x8*)(vb + mt * 2048 + c0);
                const bf16x8 vh1 = *(const bf16x8*)(vb + mt * 2048 + c1);
                oacc[mt] = __builtin_amdgcn_mfma_f32_16x16x32_bf16(vh0, pf0, oacc[mt], 0, 0, 0);
                oacc[mt] = __builtin_amdgcn_mfma_f32_16x16x32_bf16(vh1, pf1, oacc[mt], 0, 0, 0);
            }
            __builtin_amdgcn_s_barrier();
            cur ^= 1;
        }
    }

    // ---- finalize: normalized partial + l ----
    lrun += __shfl_xor(lrun, 16);
    lrun += __shfl_xor(lrun, 32);
    const float inv = lrun > 0.f ? 1.0f / lrun : 0.f;
    if (split == 0) {
        float* op = O + base + (size_t)qrow * DDIM;
        #pragma unroll
        for (int mt = 0; mt < 4; ++mt) {
            float4 o;
            o.x = oacc[mt][0] * inv;
            o.y = oacc[mt][1] * inv;
            o.z = oacc[mt][2] * inv;
            o.w = oacc[mt][3] * inv;
            *(float4*)(op + 16 * mt + 4 * g) = o;
        }
    } else {
        u16* op1 = (u16*)(ws + WS_O1) + ((size_t)bh * SDIM + qrow) * DDIM;
        #pragma unroll
        for (int mt = 0; mt < 4; ++mt) {
            u16x4 o;
            #pragma unroll
            for (int r = 0; r < 4; ++r) o[r] = f2bf(oacc[mt][r] * inv);
            *(u16x4*)(op1 + 16 * mt + 4 * g) = o;
        }
    }
    if (g == 0) {
        float* lp = (float*)(ws + WS_ML) + ((size_t)(split * 2 * HNUM + bh) * SDIM + qrow);
        *lp = lrun;
    }
}

// ---------------- combine: O = (l0*O0 + l1*O1) / (l0+l1)  (same fixed max) ----------
__global__ __launch_bounds__(NTHR)
void attn_combine(const char* __restrict__ ws, float* __restrict__ O) {
    const int t = threadIdx.x;
    const size_t grow = (size_t)blockIdx.x * 16 + (t >> 4);
    const int e4 = (t & 15) * 4;
    const float* ml = (const float*)(ws + WS_ML);
    float w0 = ml[grow];
    float w1 = ml[(size_t)2 * HNUM * SDIM + grow];
    const float swt = w0 + w1;
    const float inv = swt > 0.f ? 1.0f / swt : 0.f;
    w0 *= inv; w1 *= inv;
    float* op = O + grow * DDIM + e4;
    const float4 o0 = *(const float4*)op;
    const u16x4 o1 = *(const u16x4*)((const u16*)(ws + WS_O1) + grow * DDIM + e4);
    float4 r;
    r.x = o0.x * w0 + bf2f(o1[0]) * w1;
    r.y = o0.y * w0 + bf2f(o1[1]) * w1;
    r.z = o0.z * w0 + bf2f(o1[2]) * w1;
    r.w = o0.w * w0 + bf2f(o1[3]) * w1;
    *(float4*)op = r;
}

extern "C" void kernel_launch(void* const* d_in, const int* in_sizes, int n_in,
                              void* d_out, int out_size, void* d_ws, size_t ws_size,
                              hipStream_t stream) {
    const float* q  = (const float*)d_in[0];
    const float* k  = (const float*)d_in[1];
    const float* v  = (const float*)d_in[2];
    const int*   mk = (const int*)d_in[3];
    float* o = (float*)d_out;
    char* ws = (char*)d_ws;   // needs ~13.2 MiB

    attn_scan<<<2, NTHR, 0, stream>>>(mk, ws);

    dim3 pgrid(NT, 2 * HNUM);
    attn_prep<<<pgrid, NTHR, 0, stream>>>(k, v, ws);

    dim3 grid(SDIM / QBLK, 2 * HNUM, NSPLIT);
    attn_main<<<grid, NTHR, 0, stream>>>(q, ws, o);

    dim3 cgrid((2 * HNUM * SDIM) / 16);
    attn_combine<<<cgrid, NTHR, 0, stream>>>(ws, o);
}